// Round 10
// baseline (650.918 us; speedup 1.0000x reference)
//
#include <hip/hip_runtime.h>
#include <math.h>

// ---------------- problem constants ----------------
#define BB   16
#define LL   1024
#define BLR  (BB*LL)        // 16384 rows
#define DM   256
#define DS   16
#define FD   115
#define NF   4
#define NACTN 19
#define GH   32
#define GKN  6
#define AEM  16
#define NP   22
#define CATD 304            // cat width (16-aligned, NOT padded)
#define CATP 320            // MFMA Kp for input proj
#define KKANP 256           // KAN K padded to x32
#define KREALK 230          // 115 inputs x {ln_x, sum_basis}
#define NC   8              // scan chunks
#define CL   (LL/NC)        // 128 steps per chunk
#define TT   16             // scan time-tile staged in LDS
#define LDK  40             // LDS row stride in bf16 elems
#define XZW  544            // x_in(256) | z(256) | B(16) | C(16)

// NOTE on the KAN: the reference einsum 'big,oid->bo' has MISMATCHED grid
// subscripts (g vs d) -> contraction over i only with (sum_g basis)*(sum_d Wsp).
// NOTE on B/C: Bt = x_in @ WB^T (NOT xn @ WB^T).

typedef __attribute__((ext_vector_type(8))) short bf16x8;
typedef __attribute__((ext_vector_type(4))) float f32x4;

__device__ inline unsigned short f2bf(float f) {
    unsigned int u = __float_as_uint(f);
    u += 0x7fff + ((u >> 16) & 1);
    return (unsigned short)(u >> 16);
}
__device__ inline unsigned int f2bf2(float lo, float hi) {
    return (unsigned int)f2bf(lo) | ((unsigned int)f2bf(hi) << 16);
}

// ============ MFMA GEMM: C[M,N] = act(A_f32[M,Kreal] @ W_bf16[N,Kp]^T + bias) (+C) ==
__global__ __launch_bounds__(256) void mfma_gemm(
    const float* __restrict__ A, const unsigned short* __restrict__ W,
    const float* __restrict__ bias, float* __restrict__ C,
    int N, int Kp, int Kreal, int lda, int ldc, int act, int accum)
{
    __shared__ __align__(16) unsigned short As[128*LDK];
    __shared__ __align__(16) unsigned short Ws[128*LDK];
    const int tid = threadIdx.x;
    const int bm = blockIdx.x * 128;
    const int bn = blockIdx.y * 128;
    const int wid = tid >> 6, lane = tid & 63;
    const int wr = wid >> 1, wc = wid & 1;
    const int g = lane >> 4, r16 = lane & 15;
    const int srow = tid >> 1;            // 0..127
    const int shalf = (tid & 1) * 16;     // k offset 0/16

    f32x4 acc[4][4] = {};
    for (int k0 = 0; k0 < Kp; k0 += 32) {
        uint4 alo = make_uint4(0u,0u,0u,0u), ahi = make_uint4(0u,0u,0u,0u);
        if (k0 + shalf < Kreal) {
            const float* ap = A + (size_t)(bm + srow) * lda + k0 + shalf;
            float4 a0 = *(const float4*)(ap);
            float4 a1 = *(const float4*)(ap + 4);
            float4 a2 = *(const float4*)(ap + 8);
            float4 a3 = *(const float4*)(ap + 12);
            alo = make_uint4(f2bf2(a0.x,a0.y), f2bf2(a0.z,a0.w),
                             f2bf2(a1.x,a1.y), f2bf2(a1.z,a1.w));
            ahi = make_uint4(f2bf2(a2.x,a2.y), f2bf2(a2.z,a2.w),
                             f2bf2(a3.x,a3.y), f2bf2(a3.z,a3.w));
        }
        unsigned short* ad = &As[srow*LDK + shalf];
        *(uint4*)(ad)     = alo;
        *(uint4*)(ad + 8) = ahi;
        int n = bn + srow;
        uint4 wv0 = make_uint4(0u,0u,0u,0u), wv1 = make_uint4(0u,0u,0u,0u);
        if (n < N) {
            const unsigned short* wp = W + (size_t)n * Kp + k0 + shalf;
            wv0 = ((const uint4*)wp)[0];
            wv1 = ((const uint4*)wp)[1];
        }
        unsigned short* wd = &Ws[srow*LDK + shalf];
        *(uint4*)(wd)     = wv0;
        *(uint4*)(wd + 8) = wv1;
        __syncthreads();

        bf16x8 af[4], bfr[4];
        #pragma unroll
        for (int mi = 0; mi < 4; ++mi)
            af[mi] = *reinterpret_cast<const bf16x8*>(&As[(wr*64 + mi*16 + r16)*LDK + g*8]);
        #pragma unroll
        for (int ni = 0; ni < 4; ++ni)
            bfr[ni] = *reinterpret_cast<const bf16x8*>(&Ws[(wc*64 + ni*16 + r16)*LDK + g*8]);
        #pragma unroll
        for (int mi = 0; mi < 4; ++mi)
            #pragma unroll
            for (int ni = 0; ni < 4; ++ni)
                acc[mi][ni] = __builtin_amdgcn_mfma_f32_16x16x32_bf16(
                    af[mi], bfr[ni], acc[mi][ni], 0, 0, 0);
        __syncthreads();
    }
    #pragma unroll
    for (int mi = 0; mi < 4; ++mi) {
        #pragma unroll
        for (int j = 0; j < 4; ++j) {
            int row = bm + wr*64 + mi*16 + g*4 + j;
            float* crow = C + (size_t)row * ldc;
            #pragma unroll
            for (int ni = 0; ni < 4; ++ni) {
                int col = bn + wc*64 + ni*16 + r16;
                if (col < N) {
                    float v = acc[mi][ni][j];
                    if (bias) v += bias[col];
                    if (act == 1) v = fmaxf(v, 0.f);
                    else if (act == 2) v = fmaxf(v, 0.f) + __logf(1.f + __expf(-fabsf(v)));
                    if (accum) v += crow[col];
                    crow[col] = v;
                }
            }
        }
    }
}

// ============ fused KAN: MFMA(gen(A), WAUG) + bias -> LN(256) -> relu -> frame-mean ==
__global__ __launch_bounds__(256) void kan_fused(
    const float* __restrict__ obs, const float* __restrict__ stats,
    const float* __restrict__ lng, const float* __restrict__ lnb,
    const float* __restrict__ betap, const unsigned short* __restrict__ W,
    const float* __restrict__ kbias, const float* __restrict__ fng,
    const float* __restrict__ fnb, float* __restrict__ cat)
{
    __shared__ __align__(16) unsigned short As[128*LDK];
    __shared__ __align__(16) unsigned short Ws[256*LDK];
    __shared__ float rsum[128][2];
    __shared__ float rsq[128][2];
    const float beta = fminf(fmaxf(betap[0], 0.5f), 6.0f);
    const int tid = threadIdx.x;
    const int bm = blockIdx.x * 128;
    const int wid = tid >> 6, lane = tid & 63;
    const int wr = wid >> 1, wc = wid & 1;
    const int g = lane >> 4, r16 = lane & 15;
    const int srow = tid >> 1;
    const int shalf = (tid & 1) * 16;
    const int r = bm + srow;
    const float m  = stats[2*r];
    const float rs = stats[2*r+1];
    const float* orow = obs + (size_t)r * FD;

    f32x4 acc[4][8] = {};
    for (int k0 = 0; k0 < KKANP; k0 += 32) {
        int i0 = (k0 + shalf) >> 1;
        unsigned int pk[8];
        #pragma unroll
        for (int q = 0; q < 8; ++q) {
            int i = i0 + q;
            float xv = 0.f, sb = 0.f;
            if (i < FD) {
                float x = (orow[i] - m) * rs * lng[i] + lnb[i];
                xv = x;
                #pragma unroll
                for (int g5 = 0; g5 < 5; ++g5) {
                    float dx = x - (-1.f + 0.5f * (float)g5);
                    sb += __expf(-dx*dx*beta);
                }
            }
            pk[q] = f2bf2(xv, sb);
        }
        unsigned short* ad = &As[srow*LDK + shalf];
        *(uint4*)(ad)     = make_uint4(pk[0], pk[1], pk[2], pk[3]);
        *(uint4*)(ad + 8) = make_uint4(pk[4], pk[5], pk[6], pk[7]);
        {
            const unsigned short* wp = W + (size_t)tid * KKANP + k0;
            uint4 w0 = ((const uint4*)wp)[0];
            uint4 w1 = ((const uint4*)wp)[1];
            uint4 w2 = ((const uint4*)wp)[2];
            uint4 w3 = ((const uint4*)wp)[3];
            unsigned short* wd = &Ws[tid*LDK];
            *(uint4*)(wd)      = w0;
            *(uint4*)(wd + 8)  = w1;
            *(uint4*)(wd + 16) = w2;
            *(uint4*)(wd + 24) = w3;
        }
        __syncthreads();
        bf16x8 af[4], bfr[8];
        #pragma unroll
        for (int mi = 0; mi < 4; ++mi)
            af[mi] = *reinterpret_cast<const bf16x8*>(&As[(wr*64 + mi*16 + r16)*LDK + g*8]);
        #pragma unroll
        for (int ni = 0; ni < 8; ++ni)
            bfr[ni] = *reinterpret_cast<const bf16x8*>(&Ws[(wc*128 + ni*16 + r16)*LDK + g*8]);
        #pragma unroll
        for (int mi = 0; mi < 4; ++mi)
            #pragma unroll
            for (int ni = 0; ni < 8; ++ni)
                acc[mi][ni] = __builtin_amdgcn_mfma_f32_16x16x32_bf16(
                    af[mi], bfr[ni], acc[mi][ni], 0, 0, 0);
        __syncthreads();
    }
    float bias8[8], g8[8], b8[8];
    #pragma unroll
    for (int ni = 0; ni < 8; ++ni) {
        int col = wc*128 + ni*16 + r16;
        bias8[ni] = kbias[col]; g8[ni] = fng[col]; b8[ni] = fnb[col];
    }
    #pragma unroll
    for (int mi = 0; mi < 4; ++mi) {
        #pragma unroll
        for (int j = 0; j < 4; ++j) {
            float s = 0.f, q = 0.f;
            #pragma unroll
            for (int ni = 0; ni < 8; ++ni) {
                float v = acc[mi][ni][j] + bias8[ni];
                s += v; q += v*v;
            }
            #pragma unroll
            for (int off = 1; off < 16; off <<= 1) {
                s += __shfl_xor(s, off);
                q += __shfl_xor(q, off);
            }
            if (r16 == 0) {
                int row = wr*64 + mi*16 + g*4 + j;
                rsum[row][wc] = s; rsq[row][wc] = q;
            }
        }
    }
    __syncthreads();
    #pragma unroll
    for (int mi = 0; mi < 4; ++mi) {
        int row0 = wr*64 + mi*16 + g*4;
        float o8[8] = {0.f,0.f,0.f,0.f,0.f,0.f,0.f,0.f};
        #pragma unroll
        for (int j = 0; j < 4; ++j) {
            int row = row0 + j;
            float sm = rsum[row][0] + rsum[row][1];
            float sq = rsq[row][0] + rsq[row][1];
            float mn = sm * (1.f/256.f);
            float var = fmaxf(sq * (1.f/256.f) - mn*mn, 0.f);
            float rstd = rsqrtf(var + 1e-5f);
            #pragma unroll
            for (int ni = 0; ni < 8; ++ni) {
                float v = acc[mi][ni][j] + bias8[ni];
                v = (v - mn) * rstd * g8[ni] + b8[ni];
                o8[ni] += fmaxf(v, 0.f);
            }
        }
        int rbl = (bm + row0) >> 2;
        float* crow = cat + (size_t)rbl * CATD;
        #pragma unroll
        for (int ni = 0; ni < 8; ++ni)
            crow[wc*128 + ni*16 + r16] = o8[ni] * 0.25f;
    }
}

// ---------------- generic f32 GEMM (tiny N: BC + heads) ----------------
__global__ __launch_bounds__(256) void gemm_f32(
    const float* __restrict__ A, const float* __restrict__ W,
    const float* __restrict__ bias, float* __restrict__ C,
    int N, int K, int lda, int ldc, int act, int accum)
{
    __shared__ float As[16][68];
    __shared__ float Ws[16][68];
    const int tid = threadIdx.x;
    const int bm = blockIdx.x * 64;
    const int bn = blockIdx.y * 64;
    const int ty = tid >> 4, tx = tid & 15;
    const int lr = tid >> 2;
    const int lk = (tid & 3) * 4;
    float acc[4][4] = {{0.f,0.f,0.f,0.f},{0.f,0.f,0.f,0.f},{0.f,0.f,0.f,0.f},{0.f,0.f,0.f,0.f}};

    for (int k0 = 0; k0 < K; k0 += 16) {
        float4 av = *reinterpret_cast<const float4*>(A + (size_t)(bm + lr) * lda + k0 + lk);
        As[lk+0][lr] = av.x; As[lk+1][lr] = av.y; As[lk+2][lr] = av.z; As[lk+3][lr] = av.w;
        float4 wv = make_float4(0.f, 0.f, 0.f, 0.f);
        if (bn + lr < N)
            wv = *reinterpret_cast<const float4*>(W + (size_t)(bn + lr) * K + k0 + lk);
        Ws[lk+0][lr] = wv.x; Ws[lk+1][lr] = wv.y; Ws[lk+2][lr] = wv.z; Ws[lk+3][lr] = wv.w;
        __syncthreads();
        #pragma unroll
        for (int kk = 0; kk < 16; ++kk) {
            float4 a4 = *reinterpret_cast<const float4*>(&As[kk][ty*4]);
            float4 b4 = *reinterpret_cast<const float4*>(&Ws[kk][tx*4]);
            float aa[4] = {a4.x, a4.y, a4.z, a4.w};
            float bb[4] = {b4.x, b4.y, b4.z, b4.w};
            #pragma unroll
            for (int i = 0; i < 4; ++i)
                #pragma unroll
                for (int j = 0; j < 4; ++j)
                    acc[i][j] = fmaf(aa[i], bb[j], acc[i][j]);
        }
        __syncthreads();
    }
    #pragma unroll
    for (int i = 0; i < 4; ++i) {
        int row = bm + ty*4 + i;
        #pragma unroll
        for (int j = 0; j < 4; ++j) {
            int col = bn + tx*4 + j;
            if (col < N) {
                float v = acc[i][j];
                if (bias) v += bias[col];
                if (act == 1) v = fmaxf(v, 0.f);
                size_t o = (size_t)row * ldc + col;
                if (accum) v += C[o];
                C[o] = v;
            }
        }
    }
}

// ---------------- prep kernels ----------------
__global__ void prep_bf16(const float* __restrict__ src, unsigned short* __restrict__ dst,
                          int N, int K, int Kp)
{
    int idx = blockIdx.x * 256 + threadIdx.x;
    if (idx >= N * Kp) return;
    int n = idx / Kp, k = idx - n * Kp;
    dst[idx] = (k < K) ? f2bf(src[(size_t)n * K + k]) : (unsigned short)0;
}

__global__ void prep_waug16(const float* __restrict__ sp, const float* __restrict__ sc,
                            unsigned short* __restrict__ Wg)
{
    int idx = blockIdx.x * 256 + threadIdx.x;
    if (idx >= DM * KKANP) return;
    int o = idx >> 8, k = idx & 255;
    float v = 0.f;
    if (k < KREALK) {
        int i = k >> 1;
        if (k & 1) {
            const float* s5 = sp + ((size_t)o*FD + i)*5;
            v = s5[0] + s5[1] + s5[2] + s5[3] + s5[4];
        } else v = sc[o*FD + i];
    }
    Wg[idx] = f2bf(v);
}

__global__ void prep_wbc(const float* __restrict__ WB, const float* __restrict__ WC,
                         float* __restrict__ Wg)
{
    int idx = blockIdx.x * 256 + threadIdx.x;   // 32*256
    if (idx >= 32 * DM) return;
    int n = idx >> 8, k = idx & 255;
    Wg[idx] = (n < 16) ? WB[n*DM + k] : WC[(n-16)*DM + k];
}

// ---------------- KAN per-row LN stats ----------------
__global__ __launch_bounds__(256) void kan_stats(const float* __restrict__ obs,
                                                 float* __restrict__ stats)
{
    int row = blockIdx.x * 4 + (threadIdx.x >> 6);
    int lane = threadIdx.x & 63;
    const float* o = obs + (size_t)row * FD;
    float v0 = o[lane];
    float v1 = (lane + 64 < FD) ? o[lane + 64] : 0.f;
    float s = v0 + v1;
    for (int off = 32; off; off >>= 1) s += __shfl_xor(s, off);
    float m = s * (1.f / FD);
    float e0 = v0 - m;
    float e1 = (lane + 64 < FD) ? (v1 - m) : 0.f;
    float ss = e0*e0 + e1*e1;
    for (int off = 32; off; off >>= 1) ss += __shfl_xor(ss, off);
    if (lane == 0) {
        stats[2*row]   = m;
        stats[2*row+1] = rsqrtf(ss * (1.f / FD) + 1e-5f);
    }
}

// ---------------- graph feature -> cat[256:288] ----------------
__global__ __launch_bounds__(64) void graph_kernel(const float* __restrict__ obs,
    const float* __restrict__ gW, const float* __restrict__ ewp,
    float* __restrict__ out)
{
    __shared__ float px[NP], py[NP];
    __shared__ float nodes[NP][8];
    __shared__ float gxs[NP][GH];
    __shared__ unsigned int msk[NP];
    __shared__ float rden[NP];
    __shared__ float wgt[NP];
    const int row = blockIdx.x;
    const int lane = threadIdx.x;
    const float* fc = obs + ((size_t)row * NF + 3) * FD;
    const float* fp = obs + ((size_t)row * NF + 2) * FD;
    const float ew = ewp[0];

    if (lane < NP) {
        int i = lane;
        float p0, p1, q0, q1;
        if (i < 11) { p0 = fc[3+2*i];  p1 = fc[4+2*i];  q0 = fp[3+2*i];  q1 = fp[4+2*i]; }
        else { int ii = i-11; p0 = fc[25+2*ii]; p1 = fc[26+2*ii]; q0 = fp[25+2*ii]; q1 = fp[26+2*ii]; }
        px[i] = p0; py[i] = p1;
        float bx = fc[0], by = fc[1];
        float bd = sqrtf((p0-bx)*(p0-bx) + (p1-by)*(p1-by));
        nodes[i][0] = p0; nodes[i][1] = p1;
        nodes[i][2] = p0 - q0; nodes[i][3] = p1 - q1;
        nodes[i][4] = (i < 11) ? 0.f : 1.f;
        nodes[i][5] = __expf(-2.f * bd);
    }
    __syncthreads();
    if (lane < NP) {
        int base = (lane < 11) ? 0 : 11;
        float cx = 0.f, cy = 0.f;
        for (int j = 0; j < 11; ++j) { cx += px[base+j]; cy += py[base+j]; }
        cx *= (1.f/11.f); cy *= (1.f/11.f);
        nodes[lane][6] = px[lane] - cx;
        nodes[lane][7] = py[lane] - cy;
        unsigned sel = 0;
        for (int k = 0; k < GKN; ++k) {
            float best = 1e30f; int bj = 0;
            for (int j = 0; j < NP; ++j) {
                if (j == lane || ((sel >> j) & 1u)) continue;
                float dx = px[lane]-px[j], dy = py[lane]-py[j];
                float dd = sqrtf(dx*dx + dy*dy);
                if (dd < best) { best = dd; bj = j; }
            }
            sel |= (1u << bj);
        }
        unsigned full = sel | (1u << lane);
        msk[lane] = full;
        rden[lane] = 1.f / fmaxf((float)__popc(full), 1.f);
    }
    __syncthreads();
    for (int idx = lane; idx < NP*GH; idx += 64) {
        int i = idx >> 5, h = idx & 31;
        float s = 0.f;
        #pragma unroll
        for (int f = 0; f < 8; ++f) s += nodes[i][f] * gW[h*8 + f];
        gxs[i][h] = s;
    }
    __syncthreads();
    if (lane < NP) {
        float s = 0.f;
        for (int i = 0; i < NP; ++i) if ((msk[i] >> lane) & 1u) s += rden[i];
        wgt[lane] = (1.f - ew) + ew * s;
    }
    __syncthreads();
    if (lane < GH) {
        float s = 0.f;
        for (int j = 0; j < NP; ++j) s += wgt[j] * gxs[j][lane];
        out[(size_t)row * CATD + DM + lane] = s * (1.f/22.f);
    }
}

// ---------------- action embedding gather -> cat[288:304] ----------------
__global__ void gather_aemb(const int* __restrict__ pa, const float* __restrict__ emb,
                            float* __restrict__ out)
{
    int idx = blockIdx.x * 256 + threadIdx.x;
    int row = idx >> 4, e = idx & 15;
    out[(size_t)row * CATD + DM + GH + e] = emb[pa[row]*AEM + e];
}

// ---------------- LN over 256 cols ----------------
__global__ __launch_bounds__(256) void ln256(const float* __restrict__ X,
    const float* __restrict__ g, const float* __restrict__ b, float* __restrict__ Y)
{
    int row = blockIdx.x * 4 + (threadIdx.x >> 6);
    int lane = threadIdx.x & 63;
    const float* x = X + (size_t)row * DM;
    float4 v = reinterpret_cast<const float4*>(x)[lane];
    float s = v.x + v.y + v.z + v.w;
    for (int off = 32; off; off >>= 1) s += __shfl_xor(s, off);
    float m = s * (1.f / DM);
    float d0 = v.x-m, d1 = v.y-m, d2 = v.z-m, d3 = v.w-m;
    float ss = d0*d0 + d1*d1 + d2*d2 + d3*d3;
    for (int off = 32; off; off >>= 1) ss += __shfl_xor(ss, off);
    float rstd = rsqrtf(ss * (1.f / DM) + 1e-5f);
    int c = lane * 4;
    float4 o4 = make_float4(d0*rstd*g[c+0] + b[c+0],
                            d1*rstd*g[c+1] + b[c+1],
                            d2*rstd*g[c+2] + b[c+2],
                            d3*rstd*g[c+3] + b[c+3]);
    reinterpret_cast<float4*>(Y + (size_t)row * DM)[lane] = o4;
}

// ======== S6 chunked parallel scan, LDS-staged 16-step tiles ========
// Block = (b, chunk, dblk): 16 d x 16 s. Per tile: cooperative float4 loads.
__global__ __launch_bounds__(256) void s6_chunkA(
    const float* __restrict__ dt, const float* __restrict__ xz,
    const float* __restrict__ Alog, float* __restrict__ P, float* __restrict__ S)
{
    __shared__ float sdt[TT][16], sx[TT][16], sB[TT][16];
    const int blk = blockIdx.x;
    const int dblk = blk & 15, c = (blk >> 4) & 7, b = blk >> 7;
    const int s = threadIdx.x & 15, dl = threadIdx.x >> 4;
    const int d0 = dblk*16, d = d0 + dl;
    const float A = -__expf(Alog[d*DS + s]);
    const size_t r0 = (size_t)b*LL + c*CL;
    const int u = threadIdx.x & 63, grp = threadIdx.x >> 6;
    const int lt = u >> 2, lc = (u & 3) * 4;
    float Pv = 1.f, Sv = 0.f;
    for (int t0 = 0; t0 < CL; t0 += TT) {
        size_t rb = r0 + t0 + lt;
        if (grp == 0)      *(float4*)&sdt[lt][lc] = *(const float4*)(dt + rb*DM  + d0 + lc);
        else if (grp == 1) *(float4*)&sx[lt][lc]  = *(const float4*)(xz + rb*XZW + d0 + lc);
        else if (grp == 2) *(float4*)&sB[lt][lc]  = *(const float4*)(xz + rb*XZW + 512 + lc);
        __syncthreads();
        #pragma unroll
        for (int tt = 0; tt < TT; ++tt) {
            float dtv = sdt[tt][dl];
            float dA  = __expf(dtv * A);
            Pv *= dA;
            Sv = fmaf(dA, Sv, dtv * sx[tt][dl] * sB[tt][s]);
        }
        __syncthreads();
    }
    size_t o = (((size_t)b*NC + c)*DM + d)*DS + s;
    P[o] = Pv; S[o] = Sv;
}

__global__ __launch_bounds__(256) void s6_comb(
    const float* __restrict__ P, const float* __restrict__ S,
    const float* __restrict__ h0, float* __restrict__ hin, float* __restrict__ hout)
{
    int idx = blockIdx.x * 256 + threadIdx.x;
    int b = idx >> 12, ds = idx & 4095;
    float h = h0[idx];
    #pragma unroll
    for (int c = 0; c < NC; ++c) {
        size_t o = (((size_t)b*NC + c) << 12) + ds;
        hin[o] = h;
        h = fmaf(P[o], h, S[o]);
    }
    hout[idx] = h;
}

// ssm may alias dt: each (r,d) is loaded to LDS at tile start, stored later in the
// same tile by the SAME block; blocks own disjoint (r,d) regions -> no hazard.
// Two-phase tile body: phase 1 = pure h-recurrence banking p into registers
// (short serial chain: exp+fma only); phase 2 = 16 INDEPENDENT shuffle-reduces
// (pipeline at throughput, off the critical path).
__global__ __launch_bounds__(256) void s6_chunkC(
    const float* __restrict__ dt, const float* __restrict__ xz,
    const float* __restrict__ Alog, const float* __restrict__ hin,
    const float* __restrict__ Dp, float* __restrict__ ssm)
{
    __shared__ float sdt[TT][16], sx[TT][16], sz[TT][16], sB[TT][16], sC[TT][16];
    const int blk = blockIdx.x;
    const int dblk = blk & 15, c = (blk >> 4) & 7, b = blk >> 7;
    const int s = threadIdx.x & 15, dl = threadIdx.x >> 4;
    const int d0 = dblk*16, d = d0 + dl;
    const float A = -__expf(Alog[d*DS + s]);
    const float Dv = Dp[d];
    const size_t r0 = (size_t)b*LL + c*CL;
    const int u = threadIdx.x & 63, grp = threadIdx.x >> 6;
    const int lt = u >> 2, lc = (u & 3) * 4;
    float h = hin[(((size_t)b*NC + c)*DM + d)*DS + s];
    for (int t0 = 0; t0 < CL; t0 += TT) {
        size_t rb = r0 + t0 + lt;
        if (grp == 0)      *(float4*)&sdt[lt][lc] = *(const float4*)(dt + rb*DM  + d0 + lc);
        else if (grp == 1) *(float4*)&sx[lt][lc]  = *(const float4*)(xz + rb*XZW + d0 + lc);
        else if (grp == 2) *(float4*)&sz[lt][lc]  = *(const float4*)(xz + rb*XZW + 256 + d0 + lc);
        else {
            *(float4*)&sB[lt][lc] = *(const float4*)(xz + rb*XZW + 512 + lc);
            *(float4*)&sC[lt][lc] = *(const float4*)(xz + rb*XZW + 528 + lc);
        }
        __syncthreads();
        // phase 1: recurrence only; p_t banked in registers (static idx, unrolled)
        float preg[TT];
        #pragma unroll
        for (int tt = 0; tt < TT; ++tt) {
            float dtv = sdt[tt][dl];
            float dA  = __expf(dtv * A);
            h = fmaf(dA, h, dtv * sx[tt][dl] * sB[tt][s]);
            preg[tt] = h * sC[tt][s];
        }
        // phase 2: 16 independent 4-level reduces over s
        #pragma unroll
        for (int tt = 0; tt < TT; ++tt) {
            float p = preg[tt];
            p += __shfl_xor(p, 1);
            p += __shfl_xor(p, 2);
            p += __shfl_xor(p, 4);
            p += __shfl_xor(p, 8);
            preg[tt] = p;
        }
        if (s == 0) {
            #pragma unroll
            for (int tt = 0; tt < TT; ++tt) {
                float zv = sz[tt][dl];
                float sil = zv / (1.f + __expf(-zv));
                ssm[(r0 + t0 + tt)*DM + d] = fmaf(preg[tt], sil, sx[tt][dl] * Dv);
            }
        }
        __syncthreads();
    }
}

// ---------------- host ----------------
static inline void mgemm(hipStream_t st, const float* A, const unsigned short* W,
                         const float* bias, float* C, int M, int N, int Kp, int Kreal,
                         int lda, int ldc, int act, int accum) {
    dim3 g(M/128, (N+127)/128);
    mfma_gemm<<<g, 256, 0, st>>>(A, W, bias, C, N, Kp, Kreal, lda, ldc, act, accum);
}
static inline void gemm(hipStream_t st, const float* A, const float* W, const float* bias,
                        float* C, int M, int N, int K, int lda, int ldc, int act, int accum) {
    dim3 g(M/64, (N+63)/64);
    gemm_f32<<<g, 256, 0, st>>>(A, W, bias, C, N, K, lda, ldc, act, accum);
}

extern "C" void kernel_launch(void* const* d_in, const int* in_sizes, int n_in,
                              void* d_out, int out_size, void* d_ws, size_t ws_size,
                              hipStream_t stream) {
    (void)in_sizes; (void)n_in; (void)out_size; (void)ws_size;
    const float* obs      = (const float*)d_in[0];
    const int*   pa       = (const int*)d_in[1];
    const float* h0in[2]  = {(const float*)d_in[2], (const float*)d_in[3]};
    const float* kan_ln_g = (const float*)d_in[4];
    const float* kan_ln_b = (const float*)d_in[5];
    const float* kan_sp   = (const float*)d_in[6];
    const float* kan_sc   = (const float*)d_in[7];
    const float* kan_bias = (const float*)d_in[8];
    const float* kan_beta = (const float*)d_in[9];
    const float* fn_g     = (const float*)d_in[10];
    const float* fn_b     = (const float*)d_in[11];
    const float* gnn_W    = (const float*)d_in[12];
    const float* edge_w   = (const float*)d_in[13];
    const float* act_emb  = (const float*)d_in[14];
    const float* W_ip     = (const float*)d_in[15];
    const float* b_ip     = (const float*)d_in[16];
    const float* fl_g     = (const float*)d_in[37];
    const float* fl_b     = (const float*)d_in[38];
    const float* pW1      = (const float*)d_in[39];
    const float* pb1      = (const float*)d_in[40];
    const float* pW2      = (const float*)d_in[41];
    const float* pb2      = (const float*)d_in[42];
    const float* vW1      = (const float*)d_in[43];
    const float* vb1      = (const float*)d_in[44];
    const float* vW2      = (const float*)d_in[45];
    const float* vb2      = (const float*)d_in[46];

    // --- workspace arena (floats). Peak = 26,476,544 fl == proven footprint.
    const size_t SZ_BIG = (size_t)BLR * DM;           // 4,194,304
    float* ws = (float*)d_ws;
    float* X    = ws;                                 // residual
    float* R0   = X + SZ_BIG;                         // xn; kan-phase overlays:
    unsigned short* WIP16  = (unsigned short*)R0;                 // 256x320 bf16
    unsigned short* WAUG16 = WIP16 + (size_t)DM*CATP;             // 256x256 bf16
    float*          STATS  = (float*)(WAUG16 + (size_t)DM*KKANP); // 65536x2 f32
    float* XZBC = R0 + SZ_BIG;                        // BLR x 544 (x|z|B|C)
    float* R3   = XZBC + (size_t)BLR * XZW;           // dt -> ssm
    float* R4   = R3 + SZ_BIG;                        // cat BLRxCATD; layer overlays:
    const size_t CH = (size_t)BB * NC * DM * DS;      // 524,288
    float* Pbuf = R4;
    float* Sbuf = R4 + CH;
    float* HIN  = R4 + 2*CH;
    unsigned short* WIN16  = (unsigned short*)(R4 + 3*CH);        // 512x256 bf16
    unsigned short* WDT16  = WIN16 + 512*DM;                      // 256x256
    unsigned short* WOUT16 = WDT16 + DM*DM;                       // 256x256
    unsigned short* PW116  = WOUT16 + DM*DM;                      // 128x256
    unsigned short* VW116  = PW116 + 128*DM;                      // 64x256
    float* WBC = (float*)(VW116 + 64*DM);                         // 32x256 f32

    float* out        = (float*)d_out;
    float* out_logits = out;
    float* out_value  = out + (size_t)BLR * NACTN;
    float* out_h[2]   = {out + (size_t)BLR*NACTN + BLR,
                         out + (size_t)BLR*NACTN + BLR + (size_t)BB*DM*DS};

    // --- KAN phase (WIP16/WAUG16/STATS overlay R0, dead until layer 0) ---
    prep_waug16<<<(DM*KKANP+255)/256, 256, 0, stream>>>(kan_sp, kan_sc, WAUG16);
    prep_bf16<<<(DM*CATP+255)/256, 256, 0, stream>>>(W_ip, WIP16, DM, CATD, CATP);
    kan_stats<<<BLR*NF/4, 256, 0, stream>>>(obs, STATS);
    kan_fused<<<BLR*NF/128, 256, 0, stream>>>(
        obs, STATS, kan_ln_g, kan_ln_b, kan_beta, WAUG16, kan_bias, fn_g, fn_b, R4);
    graph_kernel<<<BLR, 64, 0, stream>>>(obs, gnn_W, edge_w, R4);
    gather_aemb<<<BLR*AEM/256, 256, 0, stream>>>(pa, act_emb, R4);

    // --- input projection: K=304 real, Kp=320 ---
    mgemm(stream, R4, WIP16, b_ip, X, BLR, DM, CATP, CATD, CATD, DM, 0, 0);

    // --- head weight preps (cat dead; R4 overlay) ---
    prep_bf16<<<(128*DM+255)/256, 256, 0, stream>>>(pW1, PW116, 128, DM, DM);
    prep_bf16<<<(64*DM+255)/256, 256, 0, stream>>>(vW1, VW116, 64, DM, DM);

    // --- two S6 layers ---
    for (int l = 0; l < 2; ++l) {
        const float* lng  = (const float*)d_in[17 + 10*l + 0];
        const float* lnb  = (const float*)d_in[17 + 10*l + 1];
        const float* Win  = (const float*)d_in[17 + 10*l + 2];
        const float* Wdt  = (const float*)d_in[17 + 10*l + 3];
        const float* bdt  = (const float*)d_in[17 + 10*l + 4];
        const float* Alog = (const float*)d_in[17 + 10*l + 5];
        const float* WBp  = (const float*)d_in[17 + 10*l + 6];
        const float* WCp  = (const float*)d_in[17 + 10*l + 7];
        const float* Dp   = (const float*)d_in[17 + 10*l + 8];
        const float* Wout = (const float*)d_in[17 + 10*l + 9];

        prep_bf16<<<(512*DM+255)/256, 256, 0, stream>>>(Win, WIN16, 512, DM, DM);
        prep_wbc<<<32, 256, 0, stream>>>(WBp, WCp, WBC);
        prep_bf16<<<(DM*DM+255)/256, 256, 0, stream>>>(Wdt, WDT16, DM, DM, DM);
        prep_bf16<<<(DM*DM+255)/256, 256, 0, stream>>>(Wout, WOUT16, DM, DM, DM);

        ln256<<<BLR/4, 256, 0, stream>>>(X, lng, lnb, R0);
        mgemm(stream, R0, WIN16, nullptr, XZBC, BLR, 512, DM, DM, DM, XZW, 0, 0);  // x|z
        gemm(stream, XZBC, WBC, nullptr, XZBC + 512, BLR, 32, DM, XZW, XZW, 0, 0); // B|C from x_in
        mgemm(stream, XZBC, WDT16, bdt, R3, BLR, DM, DM, DM, XZW, DM, 2, 0);       // dt from x_in
        s6_chunkA<<<BB*NC*16, 256, 0, stream>>>(R3, XZBC, Alog, Pbuf, Sbuf);
        s6_comb<<<BB*DM*DS/256, 256, 0, stream>>>(Pbuf, Sbuf, h0in[l], HIN, out_h[l]);
        s6_chunkC<<<BB*NC*16, 256, 0, stream>>>(R3, XZBC, Alog, HIN, Dp, R3);
        mgemm(stream, R3, WOUT16, nullptr, X, BLR, DM, DM, DM, DM, DM, 0, 1);
    }

    // --- heads (scratch in dead XZBC) ---
    float* H1 = XZBC;                     // BLR x 128
    float* H2 = XZBC + (size_t)BLR*128;   // BLR x 64
    ln256<<<BLR/4, 256, 0, stream>>>(X, fl_g, fl_b, R0);
    mgemm(stream, R0, PW116, pb1, H1, BLR, 128, DM, DM, DM, 128, 1, 0);
    gemm(stream, H1, pW2, pb2, out_logits, BLR, NACTN, 128, 128, NACTN, 0, 0);
    mgemm(stream, R0, VW116, vb1, H2, BLR, 64, DM, DM, DM, 64, 1, 0);
    gemm(stream, H2, vW2, vb2, out_value, BLR, 1, 64, 64, 1, 0, 0);
}

// Round 11
// 552.980 us; speedup vs baseline: 1.1771x; 1.1771x over previous
//
#include <hip/hip_runtime.h>
#include <math.h>

// ---------------- problem constants ----------------
#define BB   16
#define LL   1024
#define BLR  (BB*LL)        // 16384 rows
#define DM   256
#define DS   16
#define FD   115
#define NF   4
#define NACTN 19
#define GH   32
#define GKN  6
#define AEM  16
#define NP   22
#define CATD 304            // cat width (16-aligned, NOT padded)
#define CATP 320            // MFMA Kp for input proj
#define KKANP 256           // KAN K padded to x32
#define KREALK 230          // 115 inputs x {ln_x, sum_basis}
#define NC   16             // scan chunks
#define CL   (LL/NC)        // 64 steps per chunk
#define TT   16             // scan time-tile staged in LDS
#define LDK  40             // LDS row stride in bf16 elems
#define XZW  544            // x_in(256) | z(256) | B(16) | C(16)

// NOTE on the KAN: the reference einsum 'big,oid->bo' has MISMATCHED grid
// subscripts (g vs d) -> contraction over i only with (sum_g basis)*(sum_d Wsp).
// NOTE on B/C: Bt = x_in @ WB^T (NOT xn @ WB^T).
// Scan thread layout (r11): 4 s-states per thread -> LDS-pipe ops/step drop ~4x
// (r10 lesson: scan was LDS-pipe throughput bound, 7 ops/thread-step).

typedef __attribute__((ext_vector_type(8))) short bf16x8;
typedef __attribute__((ext_vector_type(4))) float f32x4;

__device__ inline unsigned short f2bf(float f) {
    unsigned int u = __float_as_uint(f);
    u += 0x7fff + ((u >> 16) & 1);
    return (unsigned short)(u >> 16);
}
__device__ inline unsigned int f2bf2(float lo, float hi) {
    return (unsigned int)f2bf(lo) | ((unsigned int)f2bf(hi) << 16);
}

// ============ MFMA GEMM: C[M,N] = act(A_f32[M,Kreal] @ W_bf16[N,Kp]^T + bias) (+C) ==
__global__ __launch_bounds__(256) void mfma_gemm(
    const float* __restrict__ A, const unsigned short* __restrict__ W,
    const float* __restrict__ bias, float* __restrict__ C,
    int N, int Kp, int Kreal, int lda, int ldc, int act, int accum)
{
    __shared__ __align__(16) unsigned short As[128*LDK];
    __shared__ __align__(16) unsigned short Ws[128*LDK];
    const int tid = threadIdx.x;
    const int bm = blockIdx.x * 128;
    const int bn = blockIdx.y * 128;
    const int wid = tid >> 6, lane = tid & 63;
    const int wr = wid >> 1, wc = wid & 1;
    const int g = lane >> 4, r16 = lane & 15;
    const int srow = tid >> 1;            // 0..127
    const int shalf = (tid & 1) * 16;     // k offset 0/16

    f32x4 acc[4][4] = {};
    for (int k0 = 0; k0 < Kp; k0 += 32) {
        uint4 alo = make_uint4(0u,0u,0u,0u), ahi = make_uint4(0u,0u,0u,0u);
        if (k0 + shalf < Kreal) {
            const float* ap = A + (size_t)(bm + srow) * lda + k0 + shalf;
            float4 a0 = *(const float4*)(ap);
            float4 a1 = *(const float4*)(ap + 4);
            float4 a2 = *(const float4*)(ap + 8);
            float4 a3 = *(const float4*)(ap + 12);
            alo = make_uint4(f2bf2(a0.x,a0.y), f2bf2(a0.z,a0.w),
                             f2bf2(a1.x,a1.y), f2bf2(a1.z,a1.w));
            ahi = make_uint4(f2bf2(a2.x,a2.y), f2bf2(a2.z,a2.w),
                             f2bf2(a3.x,a3.y), f2bf2(a3.z,a3.w));
        }
        unsigned short* ad = &As[srow*LDK + shalf];
        *(uint4*)(ad)     = alo;
        *(uint4*)(ad + 8) = ahi;
        int n = bn + srow;
        uint4 wv0 = make_uint4(0u,0u,0u,0u), wv1 = make_uint4(0u,0u,0u,0u);
        if (n < N) {
            const unsigned short* wp = W + (size_t)n * Kp + k0 + shalf;
            wv0 = ((const uint4*)wp)[0];
            wv1 = ((const uint4*)wp)[1];
        }
        unsigned short* wd = &Ws[srow*LDK + shalf];
        *(uint4*)(wd)     = wv0;
        *(uint4*)(wd + 8) = wv1;
        __syncthreads();

        bf16x8 af[4], bfr[4];
        #pragma unroll
        for (int mi = 0; mi < 4; ++mi)
            af[mi] = *reinterpret_cast<const bf16x8*>(&As[(wr*64 + mi*16 + r16)*LDK + g*8]);
        #pragma unroll
        for (int ni = 0; ni < 4; ++ni)
            bfr[ni] = *reinterpret_cast<const bf16x8*>(&Ws[(wc*64 + ni*16 + r16)*LDK + g*8]);
        #pragma unroll
        for (int mi = 0; mi < 4; ++mi)
            #pragma unroll
            for (int ni = 0; ni < 4; ++ni)
                acc[mi][ni] = __builtin_amdgcn_mfma_f32_16x16x32_bf16(
                    af[mi], bfr[ni], acc[mi][ni], 0, 0, 0);
        __syncthreads();
    }
    #pragma unroll
    for (int mi = 0; mi < 4; ++mi) {
        #pragma unroll
        for (int j = 0; j < 4; ++j) {
            int row = bm + wr*64 + mi*16 + g*4 + j;
            float* crow = C + (size_t)row * ldc;
            #pragma unroll
            for (int ni = 0; ni < 4; ++ni) {
                int col = bn + wc*64 + ni*16 + r16;
                if (col < N) {
                    float v = acc[mi][ni][j];
                    if (bias) v += bias[col];
                    if (act == 1) v = fmaxf(v, 0.f);
                    else if (act == 2) v = fmaxf(v, 0.f) + __logf(1.f + __expf(-fabsf(v)));
                    if (accum) v += crow[col];
                    crow[col] = v;
                }
            }
        }
    }
}

// ============ fused KAN: MFMA(gen(A), WAUG) + bias -> LN(256) -> relu -> frame-mean ==
__global__ __launch_bounds__(256) void kan_fused(
    const float* __restrict__ obs, const float* __restrict__ stats,
    const float* __restrict__ lng, const float* __restrict__ lnb,
    const float* __restrict__ betap, const unsigned short* __restrict__ W,
    const float* __restrict__ kbias, const float* __restrict__ fng,
    const float* __restrict__ fnb, float* __restrict__ cat)
{
    __shared__ __align__(16) unsigned short As[128*LDK];
    __shared__ __align__(16) unsigned short Ws[256*LDK];
    __shared__ float rsum[128][2];
    __shared__ float rsq[128][2];
    const float beta = fminf(fmaxf(betap[0], 0.5f), 6.0f);
    const int tid = threadIdx.x;
    const int bm = blockIdx.x * 128;
    const int wid = tid >> 6, lane = tid & 63;
    const int wr = wid >> 1, wc = wid & 1;
    const int g = lane >> 4, r16 = lane & 15;
    const int srow = tid >> 1;
    const int shalf = (tid & 1) * 16;
    const int r = bm + srow;
    const float m  = stats[2*r];
    const float rs = stats[2*r+1];
    const float* orow = obs + (size_t)r * FD;

    f32x4 acc[4][8] = {};
    for (int k0 = 0; k0 < KKANP; k0 += 32) {
        int i0 = (k0 + shalf) >> 1;
        unsigned int pk[8];
        #pragma unroll
        for (int q = 0; q < 8; ++q) {
            int i = i0 + q;
            float xv = 0.f, sb = 0.f;
            if (i < FD) {
                float x = (orow[i] - m) * rs * lng[i] + lnb[i];
                xv = x;
                #pragma unroll
                for (int g5 = 0; g5 < 5; ++g5) {
                    float dx = x - (-1.f + 0.5f * (float)g5);
                    sb += __expf(-dx*dx*beta);
                }
            }
            pk[q] = f2bf2(xv, sb);
        }
        unsigned short* ad = &As[srow*LDK + shalf];
        *(uint4*)(ad)     = make_uint4(pk[0], pk[1], pk[2], pk[3]);
        *(uint4*)(ad + 8) = make_uint4(pk[4], pk[5], pk[6], pk[7]);
        {
            const unsigned short* wp = W + (size_t)tid * KKANP + k0;
            uint4 w0 = ((const uint4*)wp)[0];
            uint4 w1 = ((const uint4*)wp)[1];
            uint4 w2 = ((const uint4*)wp)[2];
            uint4 w3 = ((const uint4*)wp)[3];
            unsigned short* wd = &Ws[tid*LDK];
            *(uint4*)(wd)      = w0;
            *(uint4*)(wd + 8)  = w1;
            *(uint4*)(wd + 16) = w2;
            *(uint4*)(wd + 24) = w3;
        }
        __syncthreads();
        bf16x8 af[4], bfr[8];
        #pragma unroll
        for (int mi = 0; mi < 4; ++mi)
            af[mi] = *reinterpret_cast<const bf16x8*>(&As[(wr*64 + mi*16 + r16)*LDK + g*8]);
        #pragma unroll
        for (int ni = 0; ni < 8; ++ni)
            bfr[ni] = *reinterpret_cast<const bf16x8*>(&Ws[(wc*128 + ni*16 + r16)*LDK + g*8]);
        #pragma unroll
        for (int mi = 0; mi < 4; ++mi)
            #pragma unroll
            for (int ni = 0; ni < 8; ++ni)
                acc[mi][ni] = __builtin_amdgcn_mfma_f32_16x16x32_bf16(
                    af[mi], bfr[ni], acc[mi][ni], 0, 0, 0);
        __syncthreads();
    }
    float bias8[8], g8[8], b8[8];
    #pragma unroll
    for (int ni = 0; ni < 8; ++ni) {
        int col = wc*128 + ni*16 + r16;
        bias8[ni] = kbias[col]; g8[ni] = fng[col]; b8[ni] = fnb[col];
    }
    #pragma unroll
    for (int mi = 0; mi < 4; ++mi) {
        #pragma unroll
        for (int j = 0; j < 4; ++j) {
            float s = 0.f, q = 0.f;
            #pragma unroll
            for (int ni = 0; ni < 8; ++ni) {
                float v = acc[mi][ni][j] + bias8[ni];
                s += v; q += v*v;
            }
            #pragma unroll
            for (int off = 1; off < 16; off <<= 1) {
                s += __shfl_xor(s, off);
                q += __shfl_xor(q, off);
            }
            if (r16 == 0) {
                int row = wr*64 + mi*16 + g*4 + j;
                rsum[row][wc] = s; rsq[row][wc] = q;
            }
        }
    }
    __syncthreads();
    #pragma unroll
    for (int mi = 0; mi < 4; ++mi) {
        int row0 = wr*64 + mi*16 + g*4;
        float o8[8] = {0.f,0.f,0.f,0.f,0.f,0.f,0.f,0.f};
        #pragma unroll
        for (int j = 0; j < 4; ++j) {
            int row = row0 + j;
            float sm = rsum[row][0] + rsum[row][1];
            float sq = rsq[row][0] + rsq[row][1];
            float mn = sm * (1.f/256.f);
            float var = fmaxf(sq * (1.f/256.f) - mn*mn, 0.f);
            float rstd = rsqrtf(var + 1e-5f);
            #pragma unroll
            for (int ni = 0; ni < 8; ++ni) {
                float v = acc[mi][ni][j] + bias8[ni];
                v = (v - mn) * rstd * g8[ni] + b8[ni];
                o8[ni] += fmaxf(v, 0.f);
            }
        }
        int rbl = (bm + row0) >> 2;
        float* crow = cat + (size_t)rbl * CATD;
        #pragma unroll
        for (int ni = 0; ni < 8; ++ni)
            crow[wc*128 + ni*16 + r16] = o8[ni] * 0.25f;
    }
}

// ---------------- generic f32 GEMM (tiny N: BC + heads) ----------------
__global__ __launch_bounds__(256) void gemm_f32(
    const float* __restrict__ A, const float* __restrict__ W,
    const float* __restrict__ bias, float* __restrict__ C,
    int N, int K, int lda, int ldc, int act, int accum)
{
    __shared__ float As[16][68];
    __shared__ float Ws[16][68];
    const int tid = threadIdx.x;
    const int bm = blockIdx.x * 64;
    const int bn = blockIdx.y * 64;
    const int ty = tid >> 4, tx = tid & 15;
    const int lr = tid >> 2;
    const int lk = (tid & 3) * 4;
    float acc[4][4] = {{0.f,0.f,0.f,0.f},{0.f,0.f,0.f,0.f},{0.f,0.f,0.f,0.f},{0.f,0.f,0.f,0.f}};

    for (int k0 = 0; k0 < K; k0 += 16) {
        float4 av = *reinterpret_cast<const float4*>(A + (size_t)(bm + lr) * lda + k0 + lk);
        As[lk+0][lr] = av.x; As[lk+1][lr] = av.y; As[lk+2][lr] = av.z; As[lk+3][lr] = av.w;
        float4 wv = make_float4(0.f, 0.f, 0.f, 0.f);
        if (bn + lr < N)
            wv = *reinterpret_cast<const float4*>(W + (size_t)(bn + lr) * K + k0 + lk);
        Ws[lk+0][lr] = wv.x; Ws[lk+1][lr] = wv.y; Ws[lk+2][lr] = wv.z; Ws[lk+3][lr] = wv.w;
        __syncthreads();
        #pragma unroll
        for (int kk = 0; kk < 16; ++kk) {
            float4 a4 = *reinterpret_cast<const float4*>(&As[kk][ty*4]);
            float4 b4 = *reinterpret_cast<const float4*>(&Ws[kk][tx*4]);
            float aa[4] = {a4.x, a4.y, a4.z, a4.w};
            float bb[4] = {b4.x, b4.y, b4.z, b4.w};
            #pragma unroll
            for (int i = 0; i < 4; ++i)
                #pragma unroll
                for (int j = 0; j < 4; ++j)
                    acc[i][j] = fmaf(aa[i], bb[j], acc[i][j]);
        }
        __syncthreads();
    }
    #pragma unroll
    for (int i = 0; i < 4; ++i) {
        int row = bm + ty*4 + i;
        #pragma unroll
        for (int j = 0; j < 4; ++j) {
            int col = bn + tx*4 + j;
            if (col < N) {
                float v = acc[i][j];
                if (bias) v += bias[col];
                if (act == 1) v = fmaxf(v, 0.f);
                size_t o = (size_t)row * ldc + col;
                if (accum) v += C[o];
                C[o] = v;
            }
        }
    }
}

// ---------------- prep kernels ----------------
__global__ void prep_bf16(const float* __restrict__ src, unsigned short* __restrict__ dst,
                          int N, int K, int Kp)
{
    int idx = blockIdx.x * 256 + threadIdx.x;
    if (idx >= N * Kp) return;
    int n = idx / Kp, k = idx - n * Kp;
    dst[idx] = (k < K) ? f2bf(src[(size_t)n * K + k]) : (unsigned short)0;
}

__global__ void prep_waug16(const float* __restrict__ sp, const float* __restrict__ sc,
                            unsigned short* __restrict__ Wg)
{
    int idx = blockIdx.x * 256 + threadIdx.x;
    if (idx >= DM * KKANP) return;
    int o = idx >> 8, k = idx & 255;
    float v = 0.f;
    if (k < KREALK) {
        int i = k >> 1;
        if (k & 1) {
            const float* s5 = sp + ((size_t)o*FD + i)*5;
            v = s5[0] + s5[1] + s5[2] + s5[3] + s5[4];
        } else v = sc[o*FD + i];
    }
    Wg[idx] = f2bf(v);
}

__global__ void prep_wbc(const float* __restrict__ WB, const float* __restrict__ WC,
                         float* __restrict__ Wg)
{
    int idx = blockIdx.x * 256 + threadIdx.x;   // 32*256
    if (idx >= 32 * DM) return;
    int n = idx >> 8, k = idx & 255;
    Wg[idx] = (n < 16) ? WB[n*DM + k] : WC[(n-16)*DM + k];
}

// ---------------- KAN per-row LN stats ----------------
__global__ __launch_bounds__(256) void kan_stats(const float* __restrict__ obs,
                                                 float* __restrict__ stats)
{
    int row = blockIdx.x * 4 + (threadIdx.x >> 6);
    int lane = threadIdx.x & 63;
    const float* o = obs + (size_t)row * FD;
    float v0 = o[lane];
    float v1 = (lane + 64 < FD) ? o[lane + 64] : 0.f;
    float s = v0 + v1;
    for (int off = 32; off; off >>= 1) s += __shfl_xor(s, off);
    float m = s * (1.f / FD);
    float e0 = v0 - m;
    float e1 = (lane + 64 < FD) ? (v1 - m) : 0.f;
    float ss = e0*e0 + e1*e1;
    for (int off = 32; off; off >>= 1) ss += __shfl_xor(ss, off);
    if (lane == 0) {
        stats[2*row]   = m;
        stats[2*row+1] = rsqrtf(ss * (1.f / FD) + 1e-5f);
    }
}

// ---------------- graph feature -> cat[256:288] ----------------
__global__ __launch_bounds__(64) void graph_kernel(const float* __restrict__ obs,
    const float* __restrict__ gW, const float* __restrict__ ewp,
    float* __restrict__ out)
{
    __shared__ float px[NP], py[NP];
    __shared__ float nodes[NP][8];
    __shared__ float gxs[NP][GH];
    __shared__ unsigned int msk[NP];
    __shared__ float rden[NP];
    __shared__ float wgt[NP];
    const int row = blockIdx.x;
    const int lane = threadIdx.x;
    const float* fc = obs + ((size_t)row * NF + 3) * FD;
    const float* fp = obs + ((size_t)row * NF + 2) * FD;
    const float ew = ewp[0];

    if (lane < NP) {
        int i = lane;
        float p0, p1, q0, q1;
        if (i < 11) { p0 = fc[3+2*i];  p1 = fc[4+2*i];  q0 = fp[3+2*i];  q1 = fp[4+2*i]; }
        else { int ii = i-11; p0 = fc[25+2*ii]; p1 = fc[26+2*ii]; q0 = fp[25+2*ii]; q1 = fp[26+2*ii]; }
        px[i] = p0; py[i] = p1;
        float bx = fc[0], by = fc[1];
        float bd = sqrtf((p0-bx)*(p0-bx) + (p1-by)*(p1-by));
        nodes[i][0] = p0; nodes[i][1] = p1;
        nodes[i][2] = p0 - q0; nodes[i][3] = p1 - q1;
        nodes[i][4] = (i < 11) ? 0.f : 1.f;
        nodes[i][5] = __expf(-2.f * bd);
    }
    __syncthreads();
    if (lane < NP) {
        int base = (lane < 11) ? 0 : 11;
        float cx = 0.f, cy = 0.f;
        for (int j = 0; j < 11; ++j) { cx += px[base+j]; cy += py[base+j]; }
        cx *= (1.f/11.f); cy *= (1.f/11.f);
        nodes[lane][6] = px[lane] - cx;
        nodes[lane][7] = py[lane] - cy;
        unsigned sel = 0;
        for (int k = 0; k < GKN; ++k) {
            float best = 1e30f; int bj = 0;
            for (int j = 0; j < NP; ++j) {
                if (j == lane || ((sel >> j) & 1u)) continue;
                float dx = px[lane]-px[j], dy = py[lane]-py[j];
                float dd = sqrtf(dx*dx + dy*dy);
                if (dd < best) { best = dd; bj = j; }
            }
            sel |= (1u << bj);
        }
        unsigned full = sel | (1u << lane);
        msk[lane] = full;
        rden[lane] = 1.f / fmaxf((float)__popc(full), 1.f);
    }
    __syncthreads();
    for (int idx = lane; idx < NP*GH; idx += 64) {
        int i = idx >> 5, h = idx & 31;
        float s = 0.f;
        #pragma unroll
        for (int f = 0; f < 8; ++f) s += nodes[i][f] * gW[h*8 + f];
        gxs[i][h] = s;
    }
    __syncthreads();
    if (lane < NP) {
        float s = 0.f;
        for (int i = 0; i < NP; ++i) if ((msk[i] >> lane) & 1u) s += rden[i];
        wgt[lane] = (1.f - ew) + ew * s;
    }
    __syncthreads();
    if (lane < GH) {
        float s = 0.f;
        for (int j = 0; j < NP; ++j) s += wgt[j] * gxs[j][lane];
        out[(size_t)row * CATD + DM + lane] = s * (1.f/22.f);
    }
}

// ---------------- action embedding gather -> cat[288:304] ----------------
__global__ void gather_aemb(const int* __restrict__ pa, const float* __restrict__ emb,
                            float* __restrict__ out)
{
    int idx = blockIdx.x * 256 + threadIdx.x;
    int row = idx >> 4, e = idx & 15;
    out[(size_t)row * CATD + DM + GH + e] = emb[pa[row]*AEM + e];
}

// ---------------- LN over 256 cols ----------------
__global__ __launch_bounds__(256) void ln256(const float* __restrict__ X,
    const float* __restrict__ g, const float* __restrict__ b, float* __restrict__ Y)
{
    int row = blockIdx.x * 4 + (threadIdx.x >> 6);
    int lane = threadIdx.x & 63;
    const float* x = X + (size_t)row * DM;
    float4 v = reinterpret_cast<const float4*>(x)[lane];
    float s = v.x + v.y + v.z + v.w;
    for (int off = 32; off; off >>= 1) s += __shfl_xor(s, off);
    float m = s * (1.f / DM);
    float d0 = v.x-m, d1 = v.y-m, d2 = v.z-m, d3 = v.w-m;
    float ss = d0*d0 + d1*d1 + d2*d2 + d3*d3;
    for (int off = 32; off; off >>= 1) ss += __shfl_xor(ss, off);
    float rstd = rsqrtf(ss * (1.f / DM) + 1e-5f);
    int c = lane * 4;
    float4 o4 = make_float4(d0*rstd*g[c+0] + b[c+0],
                            d1*rstd*g[c+1] + b[c+1],
                            d2*rstd*g[c+2] + b[c+2],
                            d3*rstd*g[c+3] + b[c+3]);
    reinterpret_cast<float4*>(Y + (size_t)row * DM)[lane] = o4;
}

// ======== S6 chunked parallel scan: 4 s-states/thread, 64 d/block ========
// Block = (b, chunk, dblk4): threads (dl=tid>>2 -> d, sg=tid&3 -> s-group of 4).
__global__ __launch_bounds__(256) void s6_chunkA(
    const float* __restrict__ dt, const float* __restrict__ xz,
    const float* __restrict__ Alog, float* __restrict__ P, float* __restrict__ S)
{
    __shared__ float sdt[TT][64], sx[TT][64];
    __shared__ __align__(16) float sB[TT][16];
    const int blk = blockIdx.x;
    const int dblk = blk & 3, c = (blk >> 2) & 15, b = blk >> 6;
    const int sg = threadIdx.x & 3, dl = threadIdx.x >> 2;
    const int d0 = dblk*64, d = d0 + dl;
    float A[4];
    #pragma unroll
    for (int k = 0; k < 4; ++k) A[k] = -__expf(Alog[d*DS + sg*4 + k]);
    const size_t r0 = (size_t)b*LL + c*CL;
    const int lt = threadIdx.x >> 4, lc = (threadIdx.x & 15) * 4;   // staging coords
    float Pv[4] = {1.f,1.f,1.f,1.f}, Sv[4] = {0.f,0.f,0.f,0.f};
    for (int t0 = 0; t0 < CL; t0 += TT) {
        size_t rb = r0 + t0 + lt;
        *(float4*)&sdt[lt][lc] = *(const float4*)(dt + rb*DM  + d0 + lc);
        *(float4*)&sx[lt][lc]  = *(const float4*)(xz + rb*XZW + d0 + lc);
        if (threadIdx.x < 64) {
            size_t rb2 = r0 + t0 + (threadIdx.x >> 2);
            *(float4*)&sB[threadIdx.x >> 2][(threadIdx.x & 3)*4] =
                *(const float4*)(xz + rb2*XZW + 512 + (threadIdx.x & 3)*4);
        }
        __syncthreads();
        #pragma unroll
        for (int tt = 0; tt < TT; ++tt) {
            float dtv = sdt[tt][dl];
            float u   = dtv * sx[tt][dl];
            float4 Bv = *(const float4*)&sB[tt][sg*4];
            float bb[4] = {Bv.x, Bv.y, Bv.z, Bv.w};
            #pragma unroll
            for (int k = 0; k < 4; ++k) {
                float dA = __expf(dtv * A[k]);
                Pv[k] *= dA;
                Sv[k] = fmaf(dA, Sv[k], u * bb[k]);
            }
        }
        __syncthreads();
    }
    size_t o = (((size_t)b*NC + c)*DM + d)*DS + sg*4;
    *(float4*)(P + o) = make_float4(Pv[0], Pv[1], Pv[2], Pv[3]);
    *(float4*)(S + o) = make_float4(Sv[0], Sv[1], Sv[2], Sv[3]);
}

__global__ __launch_bounds__(256) void s6_comb(
    const float* __restrict__ P, const float* __restrict__ S,
    const float* __restrict__ h0, float* __restrict__ hin, float* __restrict__ hout)
{
    int idx = blockIdx.x * 256 + threadIdx.x;
    int b = idx >> 12, ds = idx & 4095;
    float h = h0[idx];
    #pragma unroll
    for (int c = 0; c < NC; ++c) {
        size_t o = (((size_t)b*NC + c) << 12) + ds;
        hin[o] = h;
        h = fmaf(P[o], h, S[o]);
    }
    hout[idx] = h;
}

// ssm may alias dt: each (r,d) loaded to LDS at tile start before any store in the
// same tile by the SAME block; blocks own disjoint (rows x d-range) -> no hazard.
__global__ __launch_bounds__(256) void s6_chunkC(
    const float* __restrict__ dt, const float* __restrict__ xz,
    const float* __restrict__ Alog, const float* __restrict__ hin,
    const float* __restrict__ Dp, float* __restrict__ ssm)
{
    __shared__ float sdt[TT][64], sx[TT][64], sz[TT][64];
    __shared__ __align__(16) float sB[TT][16], sC[TT][16];
    const int blk = blockIdx.x;
    const int dblk = blk & 3, c = (blk >> 2) & 15, b = blk >> 6;
    const int sg = threadIdx.x & 3, dl = threadIdx.x >> 2;
    const int d0 = dblk*64, d = d0 + dl;
    float A[4];
    #pragma unroll
    for (int k = 0; k < 4; ++k) A[k] = -__expf(Alog[d*DS + sg*4 + k]);
    const float Dv = Dp[d];
    const size_t r0 = (size_t)b*LL + c*CL;
    const int lt = threadIdx.x >> 4, lc = (threadIdx.x & 15) * 4;
    float4 h4 = *(const float4*)(hin + (((size_t)b*NC + c)*DM + d)*DS + sg*4);
    float h[4] = {h4.x, h4.y, h4.z, h4.w};
    for (int t0 = 0; t0 < CL; t0 += TT) {
        size_t rb = r0 + t0 + lt;
        *(float4*)&sdt[lt][lc] = *(const float4*)(dt + rb*DM  + d0 + lc);
        *(float4*)&sx[lt][lc]  = *(const float4*)(xz + rb*XZW + d0 + lc);
        *(float4*)&sz[lt][lc]  = *(const float4*)(xz + rb*XZW + 256 + d0 + lc);
        if (threadIdx.x < 128) {
            size_t rb2 = r0 + t0 + ((threadIdx.x & 63) >> 2);
            int col = (threadIdx.x & 3) * 4;
            if (threadIdx.x < 64)
                *(float4*)&sB[(threadIdx.x & 63) >> 2][col] =
                    *(const float4*)(xz + rb2*XZW + 512 + col);
            else
                *(float4*)&sC[(threadIdx.x & 63) >> 2][col] =
                    *(const float4*)(xz + rb2*XZW + 528 + col);
        }
        __syncthreads();
        #pragma unroll
        for (int tt = 0; tt < TT; ++tt) {
            float dtv = sdt[tt][dl];
            float xv  = sx[tt][dl];
            float u   = dtv * xv;
            float4 Bv = *(const float4*)&sB[tt][sg*4];
            float4 Cv = *(const float4*)&sC[tt][sg*4];
            float bb[4] = {Bv.x, Bv.y, Bv.z, Bv.w};
            float cc[4] = {Cv.x, Cv.y, Cv.z, Cv.w};
            float p = 0.f;
            #pragma unroll
            for (int k = 0; k < 4; ++k) {
                float dA = __expf(dtv * A[k]);
                h[k] = fmaf(dA, h[k], u * bb[k]);
                p = fmaf(h[k], cc[k], p);
            }
            p += __shfl_xor(p, 1);
            p += __shfl_xor(p, 2);
            if (sg == 0) {
                float zv = sz[tt][dl];
                float sil = zv / (1.f + __expf(-zv));
                ssm[(r0 + t0 + tt)*DM + d] = fmaf(p, sil, xv * Dv);
            }
        }
        __syncthreads();
    }
}

// ---------------- host ----------------
static inline void mgemm(hipStream_t st, const float* A, const unsigned short* W,
                         const float* bias, float* C, int M, int N, int Kp, int Kreal,
                         int lda, int ldc, int act, int accum) {
    dim3 g(M/128, (N+127)/128);
    mfma_gemm<<<g, 256, 0, st>>>(A, W, bias, C, N, Kp, Kreal, lda, ldc, act, accum);
}
static inline void gemm(hipStream_t st, const float* A, const float* W, const float* bias,
                        float* C, int M, int N, int K, int lda, int ldc, int act, int accum) {
    dim3 g(M/64, (N+63)/64);
    gemm_f32<<<g, 256, 0, st>>>(A, W, bias, C, N, K, lda, ldc, act, accum);
}

extern "C" void kernel_launch(void* const* d_in, const int* in_sizes, int n_in,
                              void* d_out, int out_size, void* d_ws, size_t ws_size,
                              hipStream_t stream) {
    (void)in_sizes; (void)n_in; (void)out_size; (void)ws_size;
    const float* obs      = (const float*)d_in[0];
    const int*   pa       = (const int*)d_in[1];
    const float* h0in[2]  = {(const float*)d_in[2], (const float*)d_in[3]};
    const float* kan_ln_g = (const float*)d_in[4];
    const float* kan_ln_b = (const float*)d_in[5];
    const float* kan_sp   = (const float*)d_in[6];
    const float* kan_sc   = (const float*)d_in[7];
    const float* kan_bias = (const float*)d_in[8];
    const float* kan_beta = (const float*)d_in[9];
    const float* fn_g     = (const float*)d_in[10];
    const float* fn_b     = (const float*)d_in[11];
    const float* gnn_W    = (const float*)d_in[12];
    const float* edge_w   = (const float*)d_in[13];
    const float* act_emb  = (const float*)d_in[14];
    const float* W_ip     = (const float*)d_in[15];
    const float* b_ip     = (const float*)d_in[16];
    const float* fl_g     = (const float*)d_in[37];
    const float* fl_b     = (const float*)d_in[38];
    const float* pW1      = (const float*)d_in[39];
    const float* pb1      = (const float*)d_in[40];
    const float* pW2      = (const float*)d_in[41];
    const float* pb2      = (const float*)d_in[42];
    const float* vW1      = (const float*)d_in[43];
    const float* vb1      = (const float*)d_in[44];
    const float* vW2      = (const float*)d_in[45];
    const float* vb2      = (const float*)d_in[46];

    // --- workspace arena (floats). Peak <= proven footprint (26,476,544 fl).
    const size_t SZ_BIG = (size_t)BLR * DM;           // 4,194,304
    float* ws = (float*)d_ws;
    float* X    = ws;                                 // residual
    float* R0   = X + SZ_BIG;                         // xn; kan-phase overlays:
    unsigned short* WIP16  = (unsigned short*)R0;                 // 256x320 bf16
    unsigned short* WAUG16 = WIP16 + (size_t)DM*CATP;             // 256x256 bf16
    float*          STATS  = (float*)(WAUG16 + (size_t)DM*KKANP); // 65536x2 f32
    float* XZBC = R0 + SZ_BIG;                        // BLR x 544 (x|z|B|C)
    float* R3   = XZBC + (size_t)BLR * XZW;           // dt -> ssm
    float* R4   = R3 + SZ_BIG;                        // cat BLRxCATD; layer overlays:
    const size_t CH = (size_t)BB * NC * DM * DS;      // 1,048,576 (NC=16)
    float* Pbuf = R4;
    float* Sbuf = R4 + CH;
    float* HIN  = R4 + 2*CH;
    unsigned short* WIN16  = (unsigned short*)(R4 + 3*CH);        // 512x256 bf16
    unsigned short* WDT16  = WIN16 + 512*DM;                      // 256x256
    unsigned short* WOUT16 = WDT16 + DM*DM;                       // 256x256
    unsigned short* PW116  = WOUT16 + DM*DM;                      // 128x256
    unsigned short* VW116  = PW116 + 128*DM;                      // 64x256
    float* WBC = (float*)(VW116 + 64*DM);                         // 32x256 f32

    float* out        = (float*)d_out;
    float* out_logits = out;
    float* out_value  = out + (size_t)BLR * NACTN;
    float* out_h[2]   = {out + (size_t)BLR*NACTN + BLR,
                         out + (size_t)BLR*NACTN + BLR + (size_t)BB*DM*DS};

    // --- KAN phase (WIP16/WAUG16/STATS overlay R0, dead until layer 0) ---
    prep_waug16<<<(DM*KKANP+255)/256, 256, 0, stream>>>(kan_sp, kan_sc, WAUG16);
    prep_bf16<<<(DM*CATP+255)/256, 256, 0, stream>>>(W_ip, WIP16, DM, CATD, CATP);
    kan_stats<<<BLR*NF/4, 256, 0, stream>>>(obs, STATS);
    kan_fused<<<BLR*NF/128, 256, 0, stream>>>(
        obs, STATS, kan_ln_g, kan_ln_b, kan_beta, WAUG16, kan_bias, fn_g, fn_b, R4);
    graph_kernel<<<BLR, 64, 0, stream>>>(obs, gnn_W, edge_w, R4);
    gather_aemb<<<BLR*AEM/256, 256, 0, stream>>>(pa, act_emb, R4);

    // --- input projection: K=304 real, Kp=320 ---
    mgemm(stream, R4, WIP16, b_ip, X, BLR, DM, CATP, CATD, CATD, DM, 0, 0);

    // --- head weight preps (cat dead; R4 overlay) ---
    prep_bf16<<<(128*DM+255)/256, 256, 0, stream>>>(pW1, PW116, 128, DM, DM);
    prep_bf16<<<(64*DM+255)/256, 256, 0, stream>>>(vW1, VW116, 64, DM, DM);

    // --- two S6 layers ---
    for (int l = 0; l < 2; ++l) {
        const float* lng  = (const float*)d_in[17 + 10*l + 0];
        const float* lnb  = (const float*)d_in[17 + 10*l + 1];
        const float* Win  = (const float*)d_in[17 + 10*l + 2];
        const float* Wdt  = (const float*)d_in[17 + 10*l + 3];
        const float* bdt  = (const float*)d_in[17 + 10*l + 4];
        const float* Alog = (const float*)d_in[17 + 10*l + 5];
        const float* WBp  = (const float*)d_in[17 + 10*l + 6];
        const float* WCp  = (const float*)d_in[17 + 10*l + 7];
        const float* Dp   = (const float*)d_in[17 + 10*l + 8];
        const float* Wout = (const float*)d_in[17 + 10*l + 9];

        prep_bf16<<<(512*DM+255)/256, 256, 0, stream>>>(Win, WIN16, 512, DM, DM);
        prep_wbc<<<32, 256, 0, stream>>>(WBp, WCp, WBC);
        prep_bf16<<<(DM*DM+255)/256, 256, 0, stream>>>(Wdt, WDT16, DM, DM, DM);
        prep_bf16<<<(DM*DM+255)/256, 256, 0, stream>>>(Wout, WOUT16, DM, DM, DM);

        ln256<<<BLR/4, 256, 0, stream>>>(X, lng, lnb, R0);
        mgemm(stream, R0, WIN16, nullptr, XZBC, BLR, 512, DM, DM, DM, XZW, 0, 0);  // x|z
        gemm(stream, XZBC, WBC, nullptr, XZBC + 512, BLR, 32, DM, XZW, XZW, 0, 0); // B|C from x_in
        mgemm(stream, XZBC, WDT16, bdt, R3, BLR, DM, DM, DM, XZW, DM, 2, 0);       // dt from x_in
        s6_chunkA<<<BB*NC*4, 256, 0, stream>>>(R3, XZBC, Alog, Pbuf, Sbuf);
        s6_comb<<<BB*DM*DS/256, 256, 0, stream>>>(Pbuf, Sbuf, h0in[l], HIN, out_h[l]);
        s6_chunkC<<<BB*NC*4, 256, 0, stream>>>(R3, XZBC, Alog, HIN, Dp, R3);
        mgemm(stream, R3, WOUT16, nullptr, X, BLR, DM, DM, DM, DM, DM, 0, 1);
    }

    // --- heads (scratch in dead XZBC) ---
    float* H1 = XZBC;                     // BLR x 128
    float* H2 = XZBC + (size_t)BLR*128;   // BLR x 64
    ln256<<<BLR/4, 256, 0, stream>>>(X, fl_g, fl_b, R0);
    mgemm(stream, R0, PW116, pb1, H1, BLR, 128, DM, DM, DM, 128, 1, 0);
    gemm(stream, H1, pW2, pb2, out_logits, BLR, NACTN, 128, 128, NACTN, 0, 0);
    mgemm(stream, R0, VW116, vb1, H2, BLR, 64, DM, DM, DM, 64, 1, 0);
    gemm(stream, H2, vW2, vb2, out_value, BLR, 1, 64, 64, 1, 0, 0);
}

// Round 12
// 514.396 us; speedup vs baseline: 1.2654x; 1.0750x over previous
//
#include <hip/hip_runtime.h>
#include <math.h>

// ---------------- problem constants ----------------
#define BB   16
#define LL   1024
#define BLR  (BB*LL)        // 16384 rows
#define DM   256
#define DS   16
#define FD   115
#define NF   4
#define NACTN 19
#define GH   32
#define GKN  6
#define AEM  16
#define NP   22
#define CATD 304            // cat width (16-aligned, NOT padded)
#define CATP 320            // MFMA Kp for input proj
#define KKANP 256           // KAN K padded to x32
#define KREALK 230          // 115 inputs x {ln_x, sum_basis}
#define NC   16             // scan chunks
#define CL   (LL/NC)        // 64 steps per chunk
#define TT   16             // scan time-tile staged in LDS
#define LDK  40             // LDS row stride in bf16 elems
#define XZW  544            // x_in(256) | z(256) | B(16) | C(16)

// NOTE on the KAN: the reference einsum 'big,oid->bo' has MISMATCHED grid
// subscripts (g vs d) -> contraction over i only with (sum_g basis)*(sum_d Wsp).
// NOTE on B/C: Bt = x_in @ WB^T (NOT xn @ WB^T).
// r12: KAN path restructured — A/W pre-swizzled to MFMA fragment order in global;
// GEMM K-loop has NO LDS (r11 lesson: 8-way LDS write conflicts + 10% occupancy).
// Fragment-order offset (in shorts) for element (row,k):
//   (row>>4)*4096 + (k>>5)*512 + ((k>>3)&3)*128 + (row&15)*8 + (k&7)
// -> a wave's (g=lane>>4, r16=lane&15) 16B fragment loads are 1KB contiguous.

typedef __attribute__((ext_vector_type(8))) short bf16x8;
typedef __attribute__((ext_vector_type(4))) float f32x4;

__device__ inline unsigned short f2bf(float f) {
    unsigned int u = __float_as_uint(f);
    u += 0x7fff + ((u >> 16) & 1);
    return (unsigned short)(u >> 16);
}
__device__ inline unsigned int f2bf2(float lo, float hi) {
    return (unsigned int)f2bf(lo) | ((unsigned int)f2bf(hi) << 16);
}

// ============ MFMA GEMM: C[M,N] = act(A_f32[M,Kreal] @ W_bf16[N,Kp]^T + bias) (+C) ==
__global__ __launch_bounds__(256) void mfma_gemm(
    const float* __restrict__ A, const unsigned short* __restrict__ W,
    const float* __restrict__ bias, float* __restrict__ C,
    int N, int Kp, int Kreal, int lda, int ldc, int act, int accum)
{
    __shared__ __align__(16) unsigned short As[128*LDK];
    __shared__ __align__(16) unsigned short Ws[128*LDK];
    const int tid = threadIdx.x;
    const int bm = blockIdx.x * 128;
    const int bn = blockIdx.y * 128;
    const int wid = tid >> 6, lane = tid & 63;
    const int wr = wid >> 1, wc = wid & 1;
    const int g = lane >> 4, r16 = lane & 15;
    const int srow = tid >> 1;            // 0..127
    const int shalf = (tid & 1) * 16;     // k offset 0/16

    f32x4 acc[4][4] = {};
    for (int k0 = 0; k0 < Kp; k0 += 32) {
        uint4 alo = make_uint4(0u,0u,0u,0u), ahi = make_uint4(0u,0u,0u,0u);
        if (k0 + shalf < Kreal) {
            const float* ap = A + (size_t)(bm + srow) * lda + k0 + shalf;
            float4 a0 = *(const float4*)(ap);
            float4 a1 = *(const float4*)(ap + 4);
            float4 a2 = *(const float4*)(ap + 8);
            float4 a3 = *(const float4*)(ap + 12);
            alo = make_uint4(f2bf2(a0.x,a0.y), f2bf2(a0.z,a0.w),
                             f2bf2(a1.x,a1.y), f2bf2(a1.z,a1.w));
            ahi = make_uint4(f2bf2(a2.x,a2.y), f2bf2(a2.z,a2.w),
                             f2bf2(a3.x,a3.y), f2bf2(a3.z,a3.w));
        }
        unsigned short* ad = &As[srow*LDK + shalf];
        *(uint4*)(ad)     = alo;
        *(uint4*)(ad + 8) = ahi;
        int n = bn + srow;
        uint4 wv0 = make_uint4(0u,0u,0u,0u), wv1 = make_uint4(0u,0u,0u,0u);
        if (n < N) {
            const unsigned short* wp = W + (size_t)n * Kp + k0 + shalf;
            wv0 = ((const uint4*)wp)[0];
            wv1 = ((const uint4*)wp)[1];
        }
        unsigned short* wd = &Ws[srow*LDK + shalf];
        *(uint4*)(wd)     = wv0;
        *(uint4*)(wd + 8) = wv1;
        __syncthreads();

        bf16x8 af[4], bfr[4];
        #pragma unroll
        for (int mi = 0; mi < 4; ++mi)
            af[mi] = *reinterpret_cast<const bf16x8*>(&As[(wr*64 + mi*16 + r16)*LDK + g*8]);
        #pragma unroll
        for (int ni = 0; ni < 4; ++ni)
            bfr[ni] = *reinterpret_cast<const bf16x8*>(&Ws[(wc*64 + ni*16 + r16)*LDK + g*8]);
        #pragma unroll
        for (int mi = 0; mi < 4; ++mi)
            #pragma unroll
            for (int ni = 0; ni < 4; ++ni)
                acc[mi][ni] = __builtin_amdgcn_mfma_f32_16x16x32_bf16(
                    af[mi], bfr[ni], acc[mi][ni], 0, 0, 0);
        __syncthreads();
    }
    #pragma unroll
    for (int mi = 0; mi < 4; ++mi) {
        #pragma unroll
        for (int j = 0; j < 4; ++j) {
            int row = bm + wr*64 + mi*16 + g*4 + j;
            float* crow = C + (size_t)row * ldc;
            #pragma unroll
            for (int ni = 0; ni < 4; ++ni) {
                int col = bn + wc*64 + ni*16 + r16;
                if (col < N) {
                    float v = acc[mi][ni][j];
                    if (bias) v += bias[col];
                    if (act == 1) v = fmaxf(v, 0.f);
                    else if (act == 2) v = fmaxf(v, 0.f) + __logf(1.f + __expf(-fabsf(v)));
                    if (accum) v += crow[col];
                    crow[col] = v;
                }
            }
        }
    }
}

// ============ KAN stats + A-generation (fragment-swizzled bf16 out) ============
// One wave per fe-row. All lanes get LN stats via butterfly; lane l produces
// dims l and l+64 -> k-pairs (2l,2l+1) and (128+2l,129+2l).
__global__ __launch_bounds__(256) void kan_statgen(
    const float* __restrict__ obs, const float* __restrict__ lng,
    const float* __restrict__ lnb, const float* __restrict__ betap,
    unsigned short* __restrict__ AG)
{
    int row = blockIdx.x * 4 + (threadIdx.x >> 6);
    int l = threadIdx.x & 63;
    const float beta = fminf(fmaxf(betap[0], 0.5f), 6.0f);
    const float* o = obs + (size_t)row * FD;
    float v0 = o[l];
    float v1 = (l + 64 < FD) ? o[l + 64] : 0.f;
    float s = v0 + v1;
    for (int off = 32; off; off >>= 1) s += __shfl_xor(s, off);
    float m = s * (1.f / FD);
    float e0 = v0 - m;
    float e1 = (l + 64 < FD) ? (v1 - m) : 0.f;
    float ss = e0*e0 + e1*e1;
    for (int off = 32; off; off >>= 1) ss += __shfl_xor(ss, off);
    float rs = rsqrtf(ss * (1.f / FD) + 1e-5f);

    float x0 = e0 * rs * lng[l] + lnb[l];
    float sb0 = 0.f;
    #pragma unroll
    for (int g5 = 0; g5 < 5; ++g5) {
        float dx = x0 - (-1.f + 0.5f * (float)g5);
        sb0 += __expf(-dx*dx*beta);
    }
    unsigned int u0 = f2bf2(x0, sb0);
    unsigned int u1 = 0u;
    if (l + 64 < FD) {
        float x1 = e1 * rs * lng[l+64] + lnb[l+64];
        float sb1 = 0.f;
        #pragma unroll
        for (int g5 = 0; g5 < 5; ++g5) {
            float dx = x1 - (-1.f + 0.5f * (float)g5);
            sb1 += __expf(-dx*dx*beta);
        }
        u1 = f2bf2(x1, sb1);
    }
    size_t base = (size_t)(row >> 4) * 4096 + (row & 15) * 8
                + ((l >> 2) & 3) * 128 + ((2*l) & 7);
    *(unsigned int*)(AG + base + ((l >> 4)    ) * 512) = u0;
    *(unsigned int*)(AG + base + ((l >> 4) + 4) * 512) = u1;
}

// ============ KAN weights -> fragment-swizzled bf16 ============
__global__ void prep_wf16(const float* __restrict__ sp, const float* __restrict__ sc,
                          unsigned short* __restrict__ Wg)
{
    int idx = blockIdx.x * 256 + threadIdx.x;
    if (idx >= DM * KKANP) return;
    int o = idx >> 8, k = idx & 255;
    float v = 0.f;
    if (k < KREALK) {
        int i = k >> 1;
        if (k & 1) {
            const float* s5 = sp + ((size_t)o*FD + i)*5;
            v = s5[0] + s5[1] + s5[2] + s5[3] + s5[4];
        } else v = sc[o*FD + i];
    }
    Wg[(size_t)(o >> 4)*4096 + (k >> 5)*512 + ((k >> 3) & 3)*128 + (o & 15)*8 + (k & 7)]
        = f2bf(v);
}

// ============ KAN GEMM, no-LDS K-loop: fe=LN(relu?)... -> cat[0:256] ============
// 64 rows x 256 cols per block; 4 waves 2x2 (wave = 32 rows x 128 cols).
// Both operands read straight from fragment-swizzled global (coalesced 1KB/wave).
__global__ __launch_bounds__(256) void kan_gemm2(
    const unsigned short* __restrict__ AG, const unsigned short* __restrict__ WF,
    const float* __restrict__ kbias, const float* __restrict__ fng,
    const float* __restrict__ fnb, float* __restrict__ cat)
{
    __shared__ float rsum[64][2];
    __shared__ float rsq[64][2];
    const int tid = threadIdx.x;
    const int bm = blockIdx.x * 64;
    const int wid = tid >> 6, lane = tid & 63;
    const int wr = wid >> 1, wc = wid & 1;
    const int g = lane >> 4, r16 = lane & 15;

    f32x4 acc[2][8] = {};
    const unsigned short* abase = AG + ((size_t)(bm >> 4) + wr*2)*4096 + g*128 + r16*8;
    const unsigned short* wbase = WF + (size_t)(wc*8)*4096 + g*128 + r16*8;
    #pragma unroll
    for (int kk = 0; kk < 8; ++kk) {
        bf16x8 af0 = *(const bf16x8*)(abase + kk*512);
        bf16x8 af1 = *(const bf16x8*)(abase + 4096 + kk*512);
        bf16x8 bfr[8];
        #pragma unroll
        for (int ni = 0; ni < 8; ++ni)
            bfr[ni] = *(const bf16x8*)(wbase + (size_t)ni*4096 + kk*512);
        #pragma unroll
        for (int ni = 0; ni < 8; ++ni) {
            acc[0][ni] = __builtin_amdgcn_mfma_f32_16x16x32_bf16(af0, bfr[ni], acc[0][ni], 0,0,0);
            acc[1][ni] = __builtin_amdgcn_mfma_f32_16x16x32_bf16(af1, bfr[ni], acc[1][ni], 0,0,0);
        }
    }
    float bias8[8], g8[8], b8[8];
    #pragma unroll
    for (int ni = 0; ni < 8; ++ni) {
        int col = wc*128 + ni*16 + r16;
        bias8[ni] = kbias[col]; g8[ni] = fng[col]; b8[ni] = fnb[col];
    }
    #pragma unroll
    for (int mi = 0; mi < 2; ++mi) {
        #pragma unroll
        for (int j = 0; j < 4; ++j) {
            float s = 0.f, q = 0.f;
            #pragma unroll
            for (int ni = 0; ni < 8; ++ni) {
                float v = acc[mi][ni][j] + bias8[ni];
                s += v; q += v*v;
            }
            #pragma unroll
            for (int off = 1; off < 16; off <<= 1) {
                s += __shfl_xor(s, off);
                q += __shfl_xor(q, off);
            }
            if (r16 == 0) {
                int row = wr*32 + mi*16 + g*4 + j;
                rsum[row][wc] = s; rsq[row][wc] = q;
            }
        }
    }
    __syncthreads();
    #pragma unroll
    for (int mi = 0; mi < 2; ++mi) {
        int row0 = wr*32 + mi*16 + g*4;
        float o8[8] = {0.f,0.f,0.f,0.f,0.f,0.f,0.f,0.f};
        #pragma unroll
        for (int j = 0; j < 4; ++j) {
            int row = row0 + j;
            float sm = rsum[row][0] + rsum[row][1];
            float sq = rsq[row][0] + rsq[row][1];
            float mn = sm * (1.f/256.f);
            float var = fmaxf(sq * (1.f/256.f) - mn*mn, 0.f);
            float rstd = rsqrtf(var + 1e-5f);
            #pragma unroll
            for (int ni = 0; ni < 8; ++ni) {
                float v = acc[mi][ni][j] + bias8[ni];
                v = (v - mn) * rstd * g8[ni] + b8[ni];
                o8[ni] += fmaxf(v, 0.f);
            }
        }
        int rbl = (bm + row0) >> 2;
        float* crow = cat + (size_t)rbl * CATD;
        #pragma unroll
        for (int ni = 0; ni < 8; ++ni)
            crow[wc*128 + ni*16 + r16] = o8[ni] * 0.25f;
    }
}

// ---------------- generic f32 GEMM (tiny N: BC + heads) ----------------
__global__ __launch_bounds__(256) void gemm_f32(
    const float* __restrict__ A, const float* __restrict__ W,
    const float* __restrict__ bias, float* __restrict__ C,
    int N, int K, int lda, int ldc, int act, int accum)
{
    __shared__ float As[16][68];
    __shared__ float Ws[16][68];
    const int tid = threadIdx.x;
    const int bm = blockIdx.x * 64;
    const int bn = blockIdx.y * 64;
    const int ty = tid >> 4, tx = tid & 15;
    const int lr = tid >> 2;
    const int lk = (tid & 3) * 4;
    float acc[4][4] = {{0.f,0.f,0.f,0.f},{0.f,0.f,0.f,0.f},{0.f,0.f,0.f,0.f},{0.f,0.f,0.f,0.f}};

    for (int k0 = 0; k0 < K; k0 += 16) {
        float4 av = *reinterpret_cast<const float4*>(A + (size_t)(bm + lr) * lda + k0 + lk);
        As[lk+0][lr] = av.x; As[lk+1][lr] = av.y; As[lk+2][lr] = av.z; As[lk+3][lr] = av.w;
        float4 wv = make_float4(0.f, 0.f, 0.f, 0.f);
        if (bn + lr < N)
            wv = *reinterpret_cast<const float4*>(W + (size_t)(bn + lr) * K + k0 + lk);
        Ws[lk+0][lr] = wv.x; Ws[lk+1][lr] = wv.y; Ws[lk+2][lr] = wv.z; Ws[lk+3][lr] = wv.w;
        __syncthreads();
        #pragma unroll
        for (int kk = 0; kk < 16; ++kk) {
            float4 a4 = *reinterpret_cast<const float4*>(&As[kk][ty*4]);
            float4 b4 = *reinterpret_cast<const float4*>(&Ws[kk][tx*4]);
            float aa[4] = {a4.x, a4.y, a4.z, a4.w};
            float bb[4] = {b4.x, b4.y, b4.z, b4.w};
            #pragma unroll
            for (int i = 0; i < 4; ++i)
                #pragma unroll
                for (int j = 0; j < 4; ++j)
                    acc[i][j] = fmaf(aa[i], bb[j], acc[i][j]);
        }
        __syncthreads();
    }
    #pragma unroll
    for (int i = 0; i < 4; ++i) {
        int row = bm + ty*4 + i;
        #pragma unroll
        for (int j = 0; j < 4; ++j) {
            int col = bn + tx*4 + j;
            if (col < N) {
                float v = acc[i][j];
                if (bias) v += bias[col];
                if (act == 1) v = fmaxf(v, 0.f);
                size_t o = (size_t)row * ldc + col;
                if (accum) v += C[o];
                C[o] = v;
            }
        }
    }
}

// ---------------- prep kernels ----------------
__global__ void prep_bf16(const float* __restrict__ src, unsigned short* __restrict__ dst,
                          int N, int K, int Kp)
{
    int idx = blockIdx.x * 256 + threadIdx.x;
    if (idx >= N * Kp) return;
    int n = idx / Kp, k = idx - n * Kp;
    dst[idx] = (k < K) ? f2bf(src[(size_t)n * K + k]) : (unsigned short)0;
}

__global__ void prep_wbc(const float* __restrict__ WB, const float* __restrict__ WC,
                         float* __restrict__ Wg)
{
    int idx = blockIdx.x * 256 + threadIdx.x;   // 32*256
    if (idx >= 32 * DM) return;
    int n = idx >> 8, k = idx & 255;
    Wg[idx] = (n < 16) ? WB[n*DM + k] : WC[(n-16)*DM + k];
}

// ---------------- graph feature -> cat[256:288] ----------------
__global__ __launch_bounds__(64) void graph_kernel(const float* __restrict__ obs,
    const float* __restrict__ gW, const float* __restrict__ ewp,
    float* __restrict__ out)
{
    __shared__ float px[NP], py[NP];
    __shared__ float nodes[NP][8];
    __shared__ float gxs[NP][GH];
    __shared__ unsigned int msk[NP];
    __shared__ float rden[NP];
    __shared__ float wgt[NP];
    const int row = blockIdx.x;
    const int lane = threadIdx.x;
    const float* fc = obs + ((size_t)row * NF + 3) * FD;
    const float* fp = obs + ((size_t)row * NF + 2) * FD;
    const float ew = ewp[0];

    if (lane < NP) {
        int i = lane;
        float p0, p1, q0, q1;
        if (i < 11) { p0 = fc[3+2*i];  p1 = fc[4+2*i];  q0 = fp[3+2*i];  q1 = fp[4+2*i]; }
        else { int ii = i-11; p0 = fc[25+2*ii]; p1 = fc[26+2*ii]; q0 = fp[25+2*ii]; q1 = fp[26+2*ii]; }
        px[i] = p0; py[i] = p1;
        float bx = fc[0], by = fc[1];
        float bd = sqrtf((p0-bx)*(p0-bx) + (p1-by)*(p1-by));
        nodes[i][0] = p0; nodes[i][1] = p1;
        nodes[i][2] = p0 - q0; nodes[i][3] = p1 - q1;
        nodes[i][4] = (i < 11) ? 0.f : 1.f;
        nodes[i][5] = __expf(-2.f * bd);
    }
    __syncthreads();
    if (lane < NP) {
        int base = (lane < 11) ? 0 : 11;
        float cx = 0.f, cy = 0.f;
        for (int j = 0; j < 11; ++j) { cx += px[base+j]; cy += py[base+j]; }
        cx *= (1.f/11.f); cy *= (1.f/11.f);
        nodes[lane][6] = px[lane] - cx;
        nodes[lane][7] = py[lane] - cy;
        unsigned sel = 0;
        for (int k = 0; k < GKN; ++k) {
            float best = 1e30f; int bj = 0;
            for (int j = 0; j < NP; ++j) {
                if (j == lane || ((sel >> j) & 1u)) continue;
                float dx = px[lane]-px[j], dy = py[lane]-py[j];
                float dd = sqrtf(dx*dx + dy*dy);
                if (dd < best) { best = dd; bj = j; }
            }
            sel |= (1u << bj);
        }
        unsigned full = sel | (1u << lane);
        msk[lane] = full;
        rden[lane] = 1.f / fmaxf((float)__popc(full), 1.f);
    }
    __syncthreads();
    for (int idx = lane; idx < NP*GH; idx += 64) {
        int i = idx >> 5, h = idx & 31;
        float s = 0.f;
        #pragma unroll
        for (int f = 0; f < 8; ++f) s += nodes[i][f] * gW[h*8 + f];
        gxs[i][h] = s;
    }
    __syncthreads();
    if (lane < NP) {
        float s = 0.f;
        for (int i = 0; i < NP; ++i) if ((msk[i] >> lane) & 1u) s += rden[i];
        wgt[lane] = (1.f - ew) + ew * s;
    }
    __syncthreads();
    if (lane < GH) {
        float s = 0.f;
        for (int j = 0; j < NP; ++j) s += wgt[j] * gxs[j][lane];
        out[(size_t)row * CATD + DM + lane] = s * (1.f/22.f);
    }
}

// ---------------- action embedding gather -> cat[288:304] ----------------
__global__ void gather_aemb(const int* __restrict__ pa, const float* __restrict__ emb,
                            float* __restrict__ out)
{
    int idx = blockIdx.x * 256 + threadIdx.x;
    int row = idx >> 4, e = idx & 15;
    out[(size_t)row * CATD + DM + GH + e] = emb[pa[row]*AEM + e];
}

// ---------------- LN over 256 cols ----------------
__global__ __launch_bounds__(256) void ln256(const float* __restrict__ X,
    const float* __restrict__ g, const float* __restrict__ b, float* __restrict__ Y)
{
    int row = blockIdx.x * 4 + (threadIdx.x >> 6);
    int lane = threadIdx.x & 63;
    const float* x = X + (size_t)row * DM;
    float4 v = reinterpret_cast<const float4*>(x)[lane];
    float s = v.x + v.y + v.z + v.w;
    for (int off = 32; off; off >>= 1) s += __shfl_xor(s, off);
    float m = s * (1.f / DM);
    float d0 = v.x-m, d1 = v.y-m, d2 = v.z-m, d3 = v.w-m;
    float ss = d0*d0 + d1*d1 + d2*d2 + d3*d3;
    for (int off = 32; off; off >>= 1) ss += __shfl_xor(ss, off);
    float rstd = rsqrtf(ss * (1.f / DM) + 1e-5f);
    int c = lane * 4;
    float4 o4 = make_float4(d0*rstd*g[c+0] + b[c+0],
                            d1*rstd*g[c+1] + b[c+1],
                            d2*rstd*g[c+2] + b[c+2],
                            d3*rstd*g[c+3] + b[c+3]);
    reinterpret_cast<float4*>(Y + (size_t)row * DM)[lane] = o4;
}

// ======== S6 chunked parallel scan: 4 s-states/thread, 64 d/block ========
__global__ __launch_bounds__(256) void s6_chunkA(
    const float* __restrict__ dt, const float* __restrict__ xz,
    const float* __restrict__ Alog, float* __restrict__ P, float* __restrict__ S)
{
    __shared__ float sdt[TT][64], sx[TT][64];
    __shared__ __align__(16) float sB[TT][16];
    const int blk = blockIdx.x;
    const int dblk = blk & 3, c = (blk >> 2) & 15, b = blk >> 6;
    const int sg = threadIdx.x & 3, dl = threadIdx.x >> 2;
    const int d0 = dblk*64, d = d0 + dl;
    float A[4];
    #pragma unroll
    for (int k = 0; k < 4; ++k) A[k] = -__expf(Alog[d*DS + sg*4 + k]);
    const size_t r0 = (size_t)b*LL + c*CL;
    const int lt = threadIdx.x >> 4, lc = (threadIdx.x & 15) * 4;   // staging coords
    float Pv[4] = {1.f,1.f,1.f,1.f}, Sv[4] = {0.f,0.f,0.f,0.f};
    for (int t0 = 0; t0 < CL; t0 += TT) {
        size_t rb = r0 + t0 + lt;
        *(float4*)&sdt[lt][lc] = *(const float4*)(dt + rb*DM  + d0 + lc);
        *(float4*)&sx[lt][lc]  = *(const float4*)(xz + rb*XZW + d0 + lc);
        if (threadIdx.x < 64) {
            size_t rb2 = r0 + t0 + (threadIdx.x >> 2);
            *(float4*)&sB[threadIdx.x >> 2][(threadIdx.x & 3)*4] =
                *(const float4*)(xz + rb2*XZW + 512 + (threadIdx.x & 3)*4);
        }
        __syncthreads();
        #pragma unroll
        for (int tt = 0; tt < TT; ++tt) {
            float dtv = sdt[tt][dl];
            float u   = dtv * sx[tt][dl];
            float4 Bv = *(const float4*)&sB[tt][sg*4];
            float bb[4] = {Bv.x, Bv.y, Bv.z, Bv.w};
            #pragma unroll
            for (int k = 0; k < 4; ++k) {
                float dA = __expf(dtv * A[k]);
                Pv[k] *= dA;
                Sv[k] = fmaf(dA, Sv[k], u * bb[k]);
            }
        }
        __syncthreads();
    }
    size_t o = (((size_t)b*NC + c)*DM + d)*DS + sg*4;
    *(float4*)(P + o) = make_float4(Pv[0], Pv[1], Pv[2], Pv[3]);
    *(float4*)(S + o) = make_float4(Sv[0], Sv[1], Sv[2], Sv[3]);
}

__global__ __launch_bounds__(256) void s6_comb(
    const float* __restrict__ P, const float* __restrict__ S,
    const float* __restrict__ h0, float* __restrict__ hin, float* __restrict__ hout)
{
    int idx = blockIdx.x * 256 + threadIdx.x;
    int b = idx >> 12, ds = idx & 4095;
    float h = h0[idx];
    #pragma unroll
    for (int c = 0; c < NC; ++c) {
        size_t o = (((size_t)b*NC + c) << 12) + ds;
        hin[o] = h;
        h = fmaf(P[o], h, S[o]);
    }
    hout[idx] = h;
}

// ssm may alias dt: each (r,d) loaded to LDS at tile start before any store in the
// same tile by the SAME block; blocks own disjoint (rows x d-range) -> no hazard.
__global__ __launch_bounds__(256) void s6_chunkC(
    const float* __restrict__ dt, const float* __restrict__ xz,
    const float* __restrict__ Alog, const float* __restrict__ hin,
    const float* __restrict__ Dp, float* __restrict__ ssm)
{
    __shared__ float sdt[TT][64], sx[TT][64], sz[TT][64];
    __shared__ __align__(16) float sB[TT][16], sC[TT][16];
    const int blk = blockIdx.x;
    const int dblk = blk & 3, c = (blk >> 2) & 15, b = blk >> 6;
    const int sg = threadIdx.x & 3, dl = threadIdx.x >> 2;
    const int d0 = dblk*64, d = d0 + dl;
    float A[4];
    #pragma unroll
    for (int k = 0; k < 4; ++k) A[k] = -__expf(Alog[d*DS + sg*4 + k]);
    const float Dv = Dp[d];
    const size_t r0 = (size_t)b*LL + c*CL;
    const int lt = threadIdx.x >> 4, lc = (threadIdx.x & 15) * 4;
    float4 h4 = *(const float4*)(hin + (((size_t)b*NC + c)*DM + d)*DS + sg*4);
    float h[4] = {h4.x, h4.y, h4.z, h4.w};
    for (int t0 = 0; t0 < CL; t0 += TT) {
        size_t rb = r0 + t0 + lt;
        *(float4*)&sdt[lt][lc] = *(const float4*)(dt + rb*DM  + d0 + lc);
        *(float4*)&sx[lt][lc]  = *(const float4*)(xz + rb*XZW + d0 + lc);
        *(float4*)&sz[lt][lc]  = *(const float4*)(xz + rb*XZW + 256 + d0 + lc);
        if (threadIdx.x < 128) {
            size_t rb2 = r0 + t0 + ((threadIdx.x & 63) >> 2);
            int col = (threadIdx.x & 3) * 4;
            if (threadIdx.x < 64)
                *(float4*)&sB[(threadIdx.x & 63) >> 2][col] =
                    *(const float4*)(xz + rb2*XZW + 512 + col);
            else
                *(float4*)&sC[(threadIdx.x & 63) >> 2][col] =
                    *(const float4*)(xz + rb2*XZW + 528 + col);
        }
        __syncthreads();
        #pragma unroll
        for (int tt = 0; tt < TT; ++tt) {
            float dtv = sdt[tt][dl];
            float xv  = sx[tt][dl];
            float u   = dtv * xv;
            float4 Bv = *(const float4*)&sB[tt][sg*4];
            float4 Cv = *(const float4*)&sC[tt][sg*4];
            float bb[4] = {Bv.x, Bv.y, Bv.z, Bv.w};
            float cc[4] = {Cv.x, Cv.y, Cv.z, Cv.w};
            float p = 0.f;
            #pragma unroll
            for (int k = 0; k < 4; ++k) {
                float dA = __expf(dtv * A[k]);
                h[k] = fmaf(dA, h[k], u * bb[k]);
                p = fmaf(h[k], cc[k], p);
            }
            p += __shfl_xor(p, 1);
            p += __shfl_xor(p, 2);
            if (sg == 0) {
                float zv = sz[tt][dl];
                float sil = zv / (1.f + __expf(-zv));
                ssm[(r0 + t0 + tt)*DM + d] = fmaf(p, sil, xv * Dv);
            }
        }
        __syncthreads();
    }
}

// ---------------- host ----------------
static inline void mgemm(hipStream_t st, const float* A, const unsigned short* W,
                         const float* bias, float* C, int M, int N, int Kp, int Kreal,
                         int lda, int ldc, int act, int accum) {
    dim3 g(M/128, (N+127)/128);
    mfma_gemm<<<g, 256, 0, st>>>(A, W, bias, C, N, Kp, Kreal, lda, ldc, act, accum);
}
static inline void gemm(hipStream_t st, const float* A, const float* W, const float* bias,
                        float* C, int M, int N, int K, int lda, int ldc, int act, int accum) {
    dim3 g(M/64, (N+63)/64);
    gemm_f32<<<g, 256, 0, st>>>(A, W, bias, C, N, K, lda, ldc, act, accum);
}

extern "C" void kernel_launch(void* const* d_in, const int* in_sizes, int n_in,
                              void* d_out, int out_size, void* d_ws, size_t ws_size,
                              hipStream_t stream) {
    (void)in_sizes; (void)n_in; (void)out_size; (void)ws_size;
    const float* obs      = (const float*)d_in[0];
    const int*   pa       = (const int*)d_in[1];
    const float* h0in[2]  = {(const float*)d_in[2], (const float*)d_in[3]};
    const float* kan_ln_g = (const float*)d_in[4];
    const float* kan_ln_b = (const float*)d_in[5];
    const float* kan_sp   = (const float*)d_in[6];
    const float* kan_sc   = (const float*)d_in[7];
    const float* kan_bias = (const float*)d_in[8];
    const float* kan_beta = (const float*)d_in[9];
    const float* fn_g     = (const float*)d_in[10];
    const float* fn_b     = (const float*)d_in[11];
    const float* gnn_W    = (const float*)d_in[12];
    const float* edge_w   = (const float*)d_in[13];
    const float* act_emb  = (const float*)d_in[14];
    const float* W_ip     = (const float*)d_in[15];
    const float* b_ip     = (const float*)d_in[16];
    const float* fl_g     = (const float*)d_in[37];
    const float* fl_b     = (const float*)d_in[38];
    const float* pW1      = (const float*)d_in[39];
    const float* pb1      = (const float*)d_in[40];
    const float* pW2      = (const float*)d_in[41];
    const float* pb2      = (const float*)d_in[42];
    const float* vW1      = (const float*)d_in[43];
    const float* vb1      = (const float*)d_in[44];
    const float* vW2      = (const float*)d_in[45];
    const float* vb2      = (const float*)d_in[46];

    // --- workspace arena (floats). Peak <= proven footprint (26,476,544 fl).
    const size_t SZ_BIG = (size_t)BLR * DM;           // 4,194,304
    float* ws = (float*)d_ws;
    float* X    = ws;                                 // residual
    float* R0   = X + SZ_BIG;                         // xn; kan-phase overlays:
    unsigned short* WIP16 = (unsigned short*)R0;                  // 256x320 bf16
    unsigned short* WF16  = WIP16 + (size_t)DM*CATP;              // 256x256 bf16 swz
    float* XZBC = R0 + SZ_BIG;                        // BLR x 544 (x|z|B|C)
    unsigned short* AG16 = (unsigned short*)XZBC;     // 65536x256 bf16 swz (kan phase)
    float* R3   = XZBC + (size_t)BLR * XZW;           // dt -> ssm
    float* R4   = R3 + SZ_BIG;                        // cat BLRxCATD; layer overlays:
    const size_t CH = (size_t)BB * NC * DM * DS;      // 1,048,576 (NC=16)
    float* Pbuf = R4;
    float* Sbuf = R4 + CH;
    float* HIN  = R4 + 2*CH;
    unsigned short* WIN16  = (unsigned short*)(R4 + 3*CH);        // 512x256 bf16
    unsigned short* WDT16  = WIN16 + 512*DM;                      // 256x256
    unsigned short* WOUT16 = WDT16 + DM*DM;                       // 256x256
    unsigned short* PW116  = WOUT16 + DM*DM;                      // 128x256
    unsigned short* VW116  = PW116 + 128*DM;                      // 64x256
    float* WBC = (float*)(VW116 + 64*DM);                         // 32x256 f32

    float* out        = (float*)d_out;
    float* out_logits = out;
    float* out_value  = out + (size_t)BLR * NACTN;
    float* out_h[2]   = {out + (size_t)BLR*NACTN + BLR,
                         out + (size_t)BLR*NACTN + BLR + (size_t)BB*DM*DS};

    // --- KAN phase: fragment-swizzled A (in XZBC region) + W (in R0 overlay) ---
    prep_wf16<<<(DM*KKANP+255)/256, 256, 0, stream>>>(kan_sp, kan_sc, WF16);
    prep_bf16<<<(DM*CATP+255)/256, 256, 0, stream>>>(W_ip, WIP16, DM, CATD, CATP);
    kan_statgen<<<BLR*NF/4, 256, 0, stream>>>(obs, kan_ln_g, kan_ln_b, kan_beta, AG16);
    kan_gemm2<<<BLR*NF/64, 256, 0, stream>>>(AG16, WF16, kan_bias, fn_g, fn_b, R4);
    graph_kernel<<<BLR, 64, 0, stream>>>(obs, gnn_W, edge_w, R4);
    gather_aemb<<<BLR*AEM/256, 256, 0, stream>>>(pa, act_emb, R4);

    // --- input projection: K=304 real, Kp=320 ---
    mgemm(stream, R4, WIP16, b_ip, X, BLR, DM, CATP, CATD, CATD, DM, 0, 0);

    // --- head weight preps (cat dead; R4 overlay) ---
    prep_bf16<<<(128*DM+255)/256, 256, 0, stream>>>(pW1, PW116, 128, DM, DM);
    prep_bf16<<<(64*DM+255)/256, 256, 0, stream>>>(vW1, VW116, 64, DM, DM);

    // --- two S6 layers ---
    for (int l = 0; l < 2; ++l) {
        const float* lng  = (const float*)d_in[17 + 10*l + 0];
        const float* lnb  = (const float*)d_in[17 + 10*l + 1];
        const float* Win  = (const float*)d_in[17 + 10*l + 2];
        const float* Wdt  = (const float*)d_in[17 + 10*l + 3];
        const float* bdt  = (const float*)d_in[17 + 10*l + 4];
        const float* Alog = (const float*)d_in[17 + 10*l + 5];
        const float* WBp  = (const float*)d_in[17 + 10*l + 6];
        const float* WCp  = (const float*)d_in[17 + 10*l + 7];
        const float* Dp   = (const float*)d_in[17 + 10*l + 8];
        const float* Wout = (const float*)d_in[17 + 10*l + 9];

        prep_bf16<<<(512*DM+255)/256, 256, 0, stream>>>(Win, WIN16, 512, DM, DM);
        prep_wbc<<<32, 256, 0, stream>>>(WBp, WCp, WBC);
        prep_bf16<<<(DM*DM+255)/256, 256, 0, stream>>>(Wdt, WDT16, DM, DM, DM);
        prep_bf16<<<(DM*DM+255)/256, 256, 0, stream>>>(Wout, WOUT16, DM, DM, DM);

        ln256<<<BLR/4, 256, 0, stream>>>(X, lng, lnb, R0);
        mgemm(stream, R0, WIN16, nullptr, XZBC, BLR, 512, DM, DM, DM, XZW, 0, 0);  // x|z
        gemm(stream, XZBC, WBC, nullptr, XZBC + 512, BLR, 32, DM, XZW, XZW, 0, 0); // B|C from x_in
        mgemm(stream, XZBC, WDT16, bdt, R3, BLR, DM, DM, DM, XZW, DM, 2, 0);       // dt from x_in
        s6_chunkA<<<BB*NC*4, 256, 0, stream>>>(R3, XZBC, Alog, Pbuf, Sbuf);
        s6_comb<<<BB*DM*DS/256, 256, 0, stream>>>(Pbuf, Sbuf, h0in[l], HIN, out_h[l]);
        s6_chunkC<<<BB*NC*4, 256, 0, stream>>>(R3, XZBC, Alog, HIN, Dp, R3);
        mgemm(stream, R3, WOUT16, nullptr, X, BLR, DM, DM, DM, DM, DM, 0, 1);
    }

    // --- heads (scratch in dead XZBC) ---
    float* H1 = XZBC;                     // BLR x 128
    float* H2 = XZBC + (size_t)BLR*128;   // BLR x 64
    ln256<<<BLR/4, 256, 0, stream>>>(X, fl_g, fl_b, R0);
    mgemm(stream, R0, PW116, pb1, H1, BLR, 128, DM, DM, DM, 128, 1, 0);
    gemm(stream, H1, pW2, pb2, out_logits, BLR, NACTN, 128, 128, NACTN, 0, 0);
    mgemm(stream, R0, VW116, vb1, H2, BLR, 64, DM, DM, DM, 64, 1, 0);
    gemm(stream, H2, vW2, vb2, out_value, BLR, 1, 64, 64, 1, 0, 0);
}

// Round 13
// 465.520 us; speedup vs baseline: 1.3983x; 1.1050x over previous
//
#include <hip/hip_runtime.h>
#include <math.h>

// ---------------- problem constants ----------------
#define BB   16
#define LL   1024
#define BLR  (BB*LL)        // 16384 rows
#define DM   256
#define DS   16
#define FD   115
#define NF   4
#define NACTN 19
#define GH   32
#define GKN  6
#define AEM  16
#define NP   22
#define CATD 304            // cat width (16-aligned, NOT padded)
#define CATP 320            // MFMA Kp for input proj
#define KKANP 256           // KAN K padded to x32
#define KREALK 230          // 115 inputs x {ln_x, sum_basis}
#define NC   16             // scan chunks
#define CL   (LL/NC)        // 64 steps per chunk
#define TT   16             // scan time-tile staged in LDS
#define LDK  40             // LDS row stride in bf16 elems
#define XZW  800            // x_in(256) | z(256) | B(16) | C(16) | dt(256)

// NOTE KAN: reference einsum 'big,oid->bo' has MISMATCHED grid subscripts ->
// contraction over i only with (sum_g basis)*(sum_d Wsp).
// r13: B/C/dt folded into the Win GEMM via COMPOSITE weights (exact):
//   x_in = xn@Winx^T  =>  Bt = xn@(WB.Winx)^T, dt = softplus(xn@(Wdt.Winx)^T + bdt).
// WINX16[800][256] = [Win(512) | WB.Winx(16) | WC.Winx(16) | Wdt.Winx(256)].
// act==3 in mfma_gemm: softplus+bias applied only to cols >= 544.

typedef __attribute__((ext_vector_type(8))) short bf16x8;
typedef __attribute__((ext_vector_type(4))) float f32x4;

__device__ inline unsigned short f2bf(float f) {
    unsigned int u = __float_as_uint(f);
    u += 0x7fff + ((u >> 16) & 1);
    return (unsigned short)(u >> 16);
}
__device__ inline unsigned int f2bf2(float lo, float hi) {
    return (unsigned int)f2bf(lo) | ((unsigned int)f2bf(hi) << 16);
}

// ============ MFMA GEMM: C[M,N] = act(A_f32[M,Kreal] @ W_bf16[N,Kp]^T + bias) (+C) ==
__global__ __launch_bounds__(256) void mfma_gemm(
    const float* __restrict__ A, const unsigned short* __restrict__ W,
    const float* __restrict__ bias, float* __restrict__ C,
    int N, int Kp, int Kreal, int lda, int ldc, int act, int accum)
{
    __shared__ __align__(16) unsigned short As[128*LDK];
    __shared__ __align__(16) unsigned short Ws[128*LDK];
    const int tid = threadIdx.x;
    const int bm = blockIdx.x * 128;
    const int bn = blockIdx.y * 128;
    const int wid = tid >> 6, lane = tid & 63;
    const int wr = wid >> 1, wc = wid & 1;
    const int g = lane >> 4, r16 = lane & 15;
    const int srow = tid >> 1;            // 0..127
    const int shalf = (tid & 1) * 16;     // k offset 0/16

    f32x4 acc[4][4] = {};
    for (int k0 = 0; k0 < Kp; k0 += 32) {
        uint4 alo = make_uint4(0u,0u,0u,0u), ahi = make_uint4(0u,0u,0u,0u);
        if (k0 + shalf < Kreal) {
            const float* ap = A + (size_t)(bm + srow) * lda + k0 + shalf;
            float4 a0 = *(const float4*)(ap);
            float4 a1 = *(const float4*)(ap + 4);
            float4 a2 = *(const float4*)(ap + 8);
            float4 a3 = *(const float4*)(ap + 12);
            alo = make_uint4(f2bf2(a0.x,a0.y), f2bf2(a0.z,a0.w),
                             f2bf2(a1.x,a1.y), f2bf2(a1.z,a1.w));
            ahi = make_uint4(f2bf2(a2.x,a2.y), f2bf2(a2.z,a2.w),
                             f2bf2(a3.x,a3.y), f2bf2(a3.z,a3.w));
        }
        unsigned short* ad = &As[srow*LDK + shalf];
        *(uint4*)(ad)     = alo;
        *(uint4*)(ad + 8) = ahi;
        int n = bn + srow;
        uint4 wv0 = make_uint4(0u,0u,0u,0u), wv1 = make_uint4(0u,0u,0u,0u);
        if (n < N) {
            const unsigned short* wp = W + (size_t)n * Kp + k0 + shalf;
            wv0 = ((const uint4*)wp)[0];
            wv1 = ((const uint4*)wp)[1];
        }
        unsigned short* wd = &Ws[srow*LDK + shalf];
        *(uint4*)(wd)     = wv0;
        *(uint4*)(wd + 8) = wv1;
        __syncthreads();

        bf16x8 af[4], bfr[4];
        #pragma unroll
        for (int mi = 0; mi < 4; ++mi)
            af[mi] = *reinterpret_cast<const bf16x8*>(&As[(wr*64 + mi*16 + r16)*LDK + g*8]);
        #pragma unroll
        for (int ni = 0; ni < 4; ++ni)
            bfr[ni] = *reinterpret_cast<const bf16x8*>(&Ws[(wc*64 + ni*16 + r16)*LDK + g*8]);
        #pragma unroll
        for (int mi = 0; mi < 4; ++mi)
            #pragma unroll
            for (int ni = 0; ni < 4; ++ni)
                acc[mi][ni] = __builtin_amdgcn_mfma_f32_16x16x32_bf16(
                    af[mi], bfr[ni], acc[mi][ni], 0, 0, 0);
        __syncthreads();
    }
    #pragma unroll
    for (int mi = 0; mi < 4; ++mi) {
        #pragma unroll
        for (int j = 0; j < 4; ++j) {
            int row = bm + wr*64 + mi*16 + g*4 + j;
            float* crow = C + (size_t)row * ldc;
            #pragma unroll
            for (int ni = 0; ni < 4; ++ni) {
                int col = bn + wc*64 + ni*16 + r16;
                if (col < N) {
                    float v = acc[mi][ni][j];
                    if (act == 3) {
                        if (col >= 544) {
                            v += bias[col - 544];
                            v = fmaxf(v, 0.f) + __logf(1.f + __expf(-fabsf(v)));
                        }
                    } else {
                        if (bias) v += bias[col];
                        if (act == 1) v = fmaxf(v, 0.f);
                        else if (act == 2) v = fmaxf(v, 0.f) + __logf(1.f + __expf(-fabsf(v)));
                    }
                    if (accum) v += crow[col];
                    crow[col] = v;
                }
            }
        }
    }
}

// ============ KAN stats + A-generation (fragment-swizzled bf16 out) ============
__global__ __launch_bounds__(256) void kan_statgen(
    const float* __restrict__ obs, const float* __restrict__ lng,
    const float* __restrict__ lnb, const float* __restrict__ betap,
    unsigned short* __restrict__ AG)
{
    int row = blockIdx.x * 4 + (threadIdx.x >> 6);
    int l = threadIdx.x & 63;
    const float beta = fminf(fmaxf(betap[0], 0.5f), 6.0f);
    const float* o = obs + (size_t)row * FD;
    float v0 = o[l];
    float v1 = (l + 64 < FD) ? o[l + 64] : 0.f;
    float s = v0 + v1;
    for (int off = 32; off; off >>= 1) s += __shfl_xor(s, off);
    float m = s * (1.f / FD);
    float e0 = v0 - m;
    float e1 = (l + 64 < FD) ? (v1 - m) : 0.f;
    float ss = e0*e0 + e1*e1;
    for (int off = 32; off; off >>= 1) ss += __shfl_xor(ss, off);
    float rs = rsqrtf(ss * (1.f / FD) + 1e-5f);

    float x0 = e0 * rs * lng[l] + lnb[l];
    float sb0 = 0.f;
    #pragma unroll
    for (int g5 = 0; g5 < 5; ++g5) {
        float dx = x0 - (-1.f + 0.5f * (float)g5);
        sb0 += __expf(-dx*dx*beta);
    }
    unsigned int u0 = f2bf2(x0, sb0);
    unsigned int u1 = 0u;
    if (l + 64 < FD) {
        float x1 = e1 * rs * lng[l+64] + lnb[l+64];
        float sb1 = 0.f;
        #pragma unroll
        for (int g5 = 0; g5 < 5; ++g5) {
            float dx = x1 - (-1.f + 0.5f * (float)g5);
            sb1 += __expf(-dx*dx*beta);
        }
        u1 = f2bf2(x1, sb1);
    }
    size_t base = (size_t)(row >> 4) * 4096 + (row & 15) * 8
                + ((l >> 2) & 3) * 128 + ((2*l) & 7);
    *(unsigned int*)(AG + base + ((l >> 4)    ) * 512) = u0;
    *(unsigned int*)(AG + base + ((l >> 4) + 4) * 512) = u1;
}

// ============ KAN weights -> fragment-swizzled bf16 ============
__global__ void prep_wf16(const float* __restrict__ sp, const float* __restrict__ sc,
                          unsigned short* __restrict__ Wg)
{
    int idx = blockIdx.x * 256 + threadIdx.x;
    if (idx >= DM * KKANP) return;
    int o = idx >> 8, k = idx & 255;
    float v = 0.f;
    if (k < KREALK) {
        int i = k >> 1;
        if (k & 1) {
            const float* s5 = sp + ((size_t)o*FD + i)*5;
            v = s5[0] + s5[1] + s5[2] + s5[3] + s5[4];
        } else v = sc[o*FD + i];
    }
    Wg[(size_t)(o >> 4)*4096 + (k >> 5)*512 + ((k >> 3) & 3)*128 + (o & 15)*8 + (k & 7)]
        = f2bf(v);
}

// ============ KAN GEMM, no-LDS K-loop -> cat[0:256] ============
__global__ __launch_bounds__(256) void kan_gemm2(
    const unsigned short* __restrict__ AG, const unsigned short* __restrict__ WF,
    const float* __restrict__ kbias, const float* __restrict__ fng,
    const float* __restrict__ fnb, float* __restrict__ cat)
{
    __shared__ float rsum[64][2];
    __shared__ float rsq[64][2];
    const int tid = threadIdx.x;
    const int bm = blockIdx.x * 64;
    const int wid = tid >> 6, lane = tid & 63;
    const int wr = wid >> 1, wc = wid & 1;
    const int g = lane >> 4, r16 = lane & 15;

    f32x4 acc[2][8] = {};
    const unsigned short* abase = AG + ((size_t)(bm >> 4) + wr*2)*4096 + g*128 + r16*8;
    const unsigned short* wbase = WF + (size_t)(wc*8)*4096 + g*128 + r16*8;
    #pragma unroll
    for (int kk = 0; kk < 8; ++kk) {
        bf16x8 af0 = *(const bf16x8*)(abase + kk*512);
        bf16x8 af1 = *(const bf16x8*)(abase + 4096 + kk*512);
        bf16x8 bfr[8];
        #pragma unroll
        for (int ni = 0; ni < 8; ++ni)
            bfr[ni] = *(const bf16x8*)(wbase + (size_t)ni*4096 + kk*512);
        #pragma unroll
        for (int ni = 0; ni < 8; ++ni) {
            acc[0][ni] = __builtin_amdgcn_mfma_f32_16x16x32_bf16(af0, bfr[ni], acc[0][ni], 0,0,0);
            acc[1][ni] = __builtin_amdgcn_mfma_f32_16x16x32_bf16(af1, bfr[ni], acc[1][ni], 0,0,0);
        }
    }
    float bias8[8], g8[8], b8[8];
    #pragma unroll
    for (int ni = 0; ni < 8; ++ni) {
        int col = wc*128 + ni*16 + r16;
        bias8[ni] = kbias[col]; g8[ni] = fng[col]; b8[ni] = fnb[col];
    }
    #pragma unroll
    for (int mi = 0; mi < 2; ++mi) {
        #pragma unroll
        for (int j = 0; j < 4; ++j) {
            float s = 0.f, q = 0.f;
            #pragma unroll
            for (int ni = 0; ni < 8; ++ni) {
                float v = acc[mi][ni][j] + bias8[ni];
                s += v; q += v*v;
            }
            #pragma unroll
            for (int off = 1; off < 16; off <<= 1) {
                s += __shfl_xor(s, off);
                q += __shfl_xor(q, off);
            }
            if (r16 == 0) {
                int row = wr*32 + mi*16 + g*4 + j;
                rsum[row][wc] = s; rsq[row][wc] = q;
            }
        }
    }
    __syncthreads();
    #pragma unroll
    for (int mi = 0; mi < 2; ++mi) {
        int row0 = wr*32 + mi*16 + g*4;
        float o8[8] = {0.f,0.f,0.f,0.f,0.f,0.f,0.f,0.f};
        #pragma unroll
        for (int j = 0; j < 4; ++j) {
            int row = row0 + j;
            float sm = rsum[row][0] + rsum[row][1];
            float sq = rsq[row][0] + rsq[row][1];
            float mn = sm * (1.f/256.f);
            float var = fmaxf(sq * (1.f/256.f) - mn*mn, 0.f);
            float rstd = rsqrtf(var + 1e-5f);
            #pragma unroll
            for (int ni = 0; ni < 8; ++ni) {
                float v = acc[mi][ni][j] + bias8[ni];
                v = (v - mn) * rstd * g8[ni] + b8[ni];
                o8[ni] += fmaxf(v, 0.f);
            }
        }
        int rbl = (bm + row0) >> 2;
        float* crow = cat + (size_t)rbl * CATD;
        #pragma unroll
        for (int ni = 0; ni < 8; ++ni)
            crow[wc*128 + ni*16 + r16] = o8[ni] * 0.25f;
    }
}

// ---------------- generic f32 GEMM (tiny N: heads) ----------------
__global__ __launch_bounds__(256) void gemm_f32(
    const float* __restrict__ A, const float* __restrict__ W,
    const float* __restrict__ bias, float* __restrict__ C,
    int N, int K, int lda, int ldc, int act, int accum)
{
    __shared__ float As[16][68];
    __shared__ float Ws[16][68];
    const int tid = threadIdx.x;
    const int bm = blockIdx.x * 64;
    const int bn = blockIdx.y * 64;
    const int ty = tid >> 4, tx = tid & 15;
    const int lr = tid >> 2;
    const int lk = (tid & 3) * 4;
    float acc[4][4] = {{0.f,0.f,0.f,0.f},{0.f,0.f,0.f,0.f},{0.f,0.f,0.f,0.f},{0.f,0.f,0.f,0.f}};

    for (int k0 = 0; k0 < K; k0 += 16) {
        float4 av = *reinterpret_cast<const float4*>(A + (size_t)(bm + lr) * lda + k0 + lk);
        As[lk+0][lr] = av.x; As[lk+1][lr] = av.y; As[lk+2][lr] = av.z; As[lk+3][lr] = av.w;
        float4 wv = make_float4(0.f, 0.f, 0.f, 0.f);
        if (bn + lr < N)
            wv = *reinterpret_cast<const float4*>(W + (size_t)(bn + lr) * K + k0 + lk);
        Ws[lk+0][lr] = wv.x; Ws[lk+1][lr] = wv.y; Ws[lk+2][lr] = wv.z; Ws[lk+3][lr] = wv.w;
        __syncthreads();
        #pragma unroll
        for (int kk = 0; kk < 16; ++kk) {
            float4 a4 = *reinterpret_cast<const float4*>(&As[kk][ty*4]);
            float4 b4 = *reinterpret_cast<const float4*>(&Ws[kk][tx*4]);
            float aa[4] = {a4.x, a4.y, a4.z, a4.w};
            float bb[4] = {b4.x, b4.y, b4.z, b4.w};
            #pragma unroll
            for (int i = 0; i < 4; ++i)
                #pragma unroll
                for (int j = 0; j < 4; ++j)
                    acc[i][j] = fmaf(aa[i], bb[j], acc[i][j]);
        }
        __syncthreads();
    }
    #pragma unroll
    for (int i = 0; i < 4; ++i) {
        int row = bm + ty*4 + i;
        #pragma unroll
        for (int j = 0; j < 4; ++j) {
            int col = bn + tx*4 + j;
            if (col < N) {
                float v = acc[i][j];
                if (bias) v += bias[col];
                if (act == 1) v = fmaxf(v, 0.f);
                size_t o = (size_t)row * ldc + col;
                if (accum) v += C[o];
                C[o] = v;
            }
        }
    }
}

// ---------------- prep kernels ----------------
__global__ void prep_bf16(const float* __restrict__ src, unsigned short* __restrict__ dst,
                          int N, int K, int Kp)
{
    int idx = blockIdx.x * 256 + threadIdx.x;
    if (idx >= N * Kp) return;
    int n = idx / Kp, k = idx - n * Kp;
    dst[idx] = (k < K) ? f2bf(src[(size_t)n * K + k]) : (unsigned short)0;
}

// Per-layer weight prep: WINX16[800][256] = [Win | WB.Winx | WC.Winx | Wdt.Winx],
// WOUT16[256][256]. Composite rows are 256-long dots vs Win rows 0..255 (= Winx).
__global__ void prep_layerw(
    const float* __restrict__ Win, const float* __restrict__ WB,
    const float* __restrict__ WC, const float* __restrict__ Wdt,
    const float* __restrict__ Wout,
    unsigned short* __restrict__ WINX16, unsigned short* __restrict__ WOUT16)
{
    int idx = blockIdx.x * 256 + threadIdx.x;
    if (idx < 512*256) {                       // straight Win convert
        WINX16[idx] = f2bf(Win[idx]);
    } else if (idx < 544*256) {                // B|C composites (rows 512..543)
        int j2 = idx - 512*256;
        int n = j2 >> 8, k = j2 & 255;
        const float* src = (n < 16) ? (WB + n*DM) : (WC + (n-16)*DM);
        float acc = 0.f;
        for (int j = 0; j < DM; ++j)
            acc = fmaf(src[j], Win[(size_t)j*DM + k], acc);
        WINX16[idx] = f2bf(acc);
    } else if (idx < 800*256) {                // dt composite (rows 544..799)
        int j2 = idx - 544*256;
        int n = j2 >> 8, k = j2 & 255;
        const float* src = Wdt + (size_t)n*DM;
        float acc = 0.f;
        for (int j = 0; j < DM; ++j)
            acc = fmaf(src[j], Win[(size_t)j*DM + k], acc);
        WINX16[idx] = f2bf(acc);
    } else if (idx < 800*256 + 256*256) {      // Wout convert
        int j2 = idx - 800*256;
        WOUT16[j2] = f2bf(Wout[j2]);
    }
}

// ---------------- graph feature -> cat[256:288] ----------------
__global__ __launch_bounds__(64) void graph_kernel(const float* __restrict__ obs,
    const float* __restrict__ gW, const float* __restrict__ ewp,
    float* __restrict__ out)
{
    __shared__ float px[NP], py[NP];
    __shared__ float nodes[NP][8];
    __shared__ float gxs[NP][GH];
    __shared__ unsigned int msk[NP];
    __shared__ float rden[NP];
    __shared__ float wgt[NP];
    const int row = blockIdx.x;
    const int lane = threadIdx.x;
    const float* fc = obs + ((size_t)row * NF + 3) * FD;
    const float* fp = obs + ((size_t)row * NF + 2) * FD;
    const float ew = ewp[0];

    if (lane < NP) {
        int i = lane;
        float p0, p1, q0, q1;
        if (i < 11) { p0 = fc[3+2*i];  p1 = fc[4+2*i];  q0 = fp[3+2*i];  q1 = fp[4+2*i]; }
        else { int ii = i-11; p0 = fc[25+2*ii]; p1 = fc[26+2*ii]; q0 = fp[25+2*ii]; q1 = fp[26+2*ii]; }
        px[i] = p0; py[i] = p1;
        float bx = fc[0], by = fc[1];
        float bd = sqrtf((p0-bx)*(p0-bx) + (p1-by)*(p1-by));
        nodes[i][0] = p0; nodes[i][1] = p1;
        nodes[i][2] = p0 - q0; nodes[i][3] = p1 - q1;
        nodes[i][4] = (i < 11) ? 0.f : 1.f;
        nodes[i][5] = __expf(-2.f * bd);
    }
    __syncthreads();
    if (lane < NP) {
        int base = (lane < 11) ? 0 : 11;
        float cx = 0.f, cy = 0.f;
        for (int j = 0; j < 11; ++j) { cx += px[base+j]; cy += py[base+j]; }
        cx *= (1.f/11.f); cy *= (1.f/11.f);
        nodes[lane][6] = px[lane] - cx;
        nodes[lane][7] = py[lane] - cy;
        unsigned sel = 0;
        for (int k = 0; k < GKN; ++k) {
            float best = 1e30f; int bj = 0;
            for (int j = 0; j < NP; ++j) {
                if (j == lane || ((sel >> j) & 1u)) continue;
                float dx = px[lane]-px[j], dy = py[lane]-py[j];
                float dd = sqrtf(dx*dx + dy*dy);
                if (dd < best) { best = dd; bj = j; }
            }
            sel |= (1u << bj);
        }
        unsigned full = sel | (1u << lane);
        msk[lane] = full;
        rden[lane] = 1.f / fmaxf((float)__popc(full), 1.f);
    }
    __syncthreads();
    for (int idx = lane; idx < NP*GH; idx += 64) {
        int i = idx >> 5, h = idx & 31;
        float s = 0.f;
        #pragma unroll
        for (int f = 0; f < 8; ++f) s += nodes[i][f] * gW[h*8 + f];
        gxs[i][h] = s;
    }
    __syncthreads();
    if (lane < NP) {
        float s = 0.f;
        for (int i = 0; i < NP; ++i) if ((msk[i] >> lane) & 1u) s += rden[i];
        wgt[lane] = (1.f - ew) + ew * s;
    }
    __syncthreads();
    if (lane < GH) {
        float s = 0.f;
        for (int j = 0; j < NP; ++j) s += wgt[j] * gxs[j][lane];
        out[(size_t)row * CATD + DM + lane] = s * (1.f/22.f);
    }
}

// ---------------- action embedding gather -> cat[288:304] ----------------
__global__ void gather_aemb(const int* __restrict__ pa, const float* __restrict__ emb,
                            float* __restrict__ out)
{
    int idx = blockIdx.x * 256 + threadIdx.x;
    int row = idx >> 4, e = idx & 15;
    out[(size_t)row * CATD + DM + GH + e] = emb[pa[row]*AEM + e];
}

// ---------------- LN over 256 cols ----------------
__global__ __launch_bounds__(256) void ln256(const float* __restrict__ X,
    const float* __restrict__ g, const float* __restrict__ b, float* __restrict__ Y)
{
    int row = blockIdx.x * 4 + (threadIdx.x >> 6);
    int lane = threadIdx.x & 63;
    const float* x = X + (size_t)row * DM;
    float4 v = reinterpret_cast<const float4*>(x)[lane];
    float s = v.x + v.y + v.z + v.w;
    for (int off = 32; off; off >>= 1) s += __shfl_xor(s, off);
    float m = s * (1.f / DM);
    float d0 = v.x-m, d1 = v.y-m, d2 = v.z-m, d3 = v.w-m;
    float ss = d0*d0 + d1*d1 + d2*d2 + d3*d3;
    for (int off = 32; off; off >>= 1) ss += __shfl_xor(ss, off);
    float rstd = rsqrtf(ss * (1.f / DM) + 1e-5f);
    int c = lane * 4;
    float4 o4 = make_float4(d0*rstd*g[c+0] + b[c+0],
                            d1*rstd*g[c+1] + b[c+1],
                            d2*rstd*g[c+2] + b[c+2],
                            d3*rstd*g[c+3] + b[c+3]);
    reinterpret_cast<float4*>(Y + (size_t)row * DM)[lane] = o4;
}

// ======== S6 chunked parallel scan: 4 s-states/thread, 64 d/block ========
// XZBC row layout: [0:256)=x, [256:512)=z, [512:528)=B, [528:544)=C, [544:800)=dt.
__global__ __launch_bounds__(256) void s6_chunkA(
    const float* __restrict__ xz, const float* __restrict__ Alog,
    float* __restrict__ P, float* __restrict__ S)
{
    __shared__ float sdt[TT][64], sx[TT][64];
    __shared__ __align__(16) float sB[TT][16];
    const int blk = blockIdx.x;
    const int dblk = blk & 3, c = (blk >> 2) & 15, b = blk >> 6;
    const int sg = threadIdx.x & 3, dl = threadIdx.x >> 2;
    const int d0 = dblk*64, d = d0 + dl;
    float A[4];
    #pragma unroll
    for (int k = 0; k < 4; ++k) A[k] = -__expf(Alog[d*DS + sg*4 + k]);
    const size_t r0 = (size_t)b*LL + c*CL;
    const int lt = threadIdx.x >> 4, lc = (threadIdx.x & 15) * 4;
    float Pv[4] = {1.f,1.f,1.f,1.f}, Sv[4] = {0.f,0.f,0.f,0.f};
    for (int t0 = 0; t0 < CL; t0 += TT) {
        size_t rb = r0 + t0 + lt;
        *(float4*)&sdt[lt][lc] = *(const float4*)(xz + rb*XZW + 544 + d0 + lc);
        *(float4*)&sx[lt][lc]  = *(const float4*)(xz + rb*XZW + d0 + lc);
        if (threadIdx.x < 64) {
            size_t rb2 = r0 + t0 + (threadIdx.x >> 2);
            *(float4*)&sB[threadIdx.x >> 2][(threadIdx.x & 3)*4] =
                *(const float4*)(xz + rb2*XZW + 512 + (threadIdx.x & 3)*4);
        }
        __syncthreads();
        #pragma unroll
        for (int tt = 0; tt < TT; ++tt) {
            float dtv = sdt[tt][dl];
            float u   = dtv * sx[tt][dl];
            float4 Bv = *(const float4*)&sB[tt][sg*4];
            float bb[4] = {Bv.x, Bv.y, Bv.z, Bv.w};
            #pragma unroll
            for (int k = 0; k < 4; ++k) {
                float dA = __expf(dtv * A[k]);
                Pv[k] *= dA;
                Sv[k] = fmaf(dA, Sv[k], u * bb[k]);
            }
        }
        __syncthreads();
    }
    size_t o = (((size_t)b*NC + c)*DM + d)*DS + sg*4;
    *(float4*)(P + o) = make_float4(Pv[0], Pv[1], Pv[2], Pv[3]);
    *(float4*)(S + o) = make_float4(Sv[0], Sv[1], Sv[2], Sv[3]);
}

__global__ __launch_bounds__(256) void s6_comb(
    const float* __restrict__ P, const float* __restrict__ S,
    const float* __restrict__ h0, float* __restrict__ hin, float* __restrict__ hout)
{
    int idx = blockIdx.x * 256 + threadIdx.x;
    int b = idx >> 12, ds = idx & 4095;
    float h = h0[idx];
    #pragma unroll
    for (int c = 0; c < NC; ++c) {
        size_t o = (((size_t)b*NC + c) << 12) + ds;
        hin[o] = h;
        h = fmaf(P[o], h, S[o]);
    }
    hout[idx] = h;
}

// ssm -> separate buffer (no aliasing with inputs at all).
__global__ __launch_bounds__(256) void s6_chunkC(
    const float* __restrict__ xz, const float* __restrict__ Alog,
    const float* __restrict__ hin, const float* __restrict__ Dp,
    float* __restrict__ ssm)
{
    __shared__ float sdt[TT][64], sx[TT][64], sz[TT][64];
    __shared__ __align__(16) float sB[TT][16], sC[TT][16];
    const int blk = blockIdx.x;
    const int dblk = blk & 3, c = (blk >> 2) & 15, b = blk >> 6;
    const int sg = threadIdx.x & 3, dl = threadIdx.x >> 2;
    const int d0 = dblk*64, d = d0 + dl;
    float A[4];
    #pragma unroll
    for (int k = 0; k < 4; ++k) A[k] = -__expf(Alog[d*DS + sg*4 + k]);
    const float Dv = Dp[d];
    const size_t r0 = (size_t)b*LL + c*CL;
    const int lt = threadIdx.x >> 4, lc = (threadIdx.x & 15) * 4;
    float4 h4 = *(const float4*)(hin + (((size_t)b*NC + c)*DM + d)*DS + sg*4);
    float h[4] = {h4.x, h4.y, h4.z, h4.w};
    for (int t0 = 0; t0 < CL; t0 += TT) {
        size_t rb = r0 + t0 + lt;
        *(float4*)&sdt[lt][lc] = *(const float4*)(xz + rb*XZW + 544 + d0 + lc);
        *(float4*)&sx[lt][lc]  = *(const float4*)(xz + rb*XZW + d0 + lc);
        *(float4*)&sz[lt][lc]  = *(const float4*)(xz + rb*XZW + 256 + d0 + lc);
        if (threadIdx.x < 128) {
            size_t rb2 = r0 + t0 + ((threadIdx.x & 63) >> 2);
            int col = (threadIdx.x & 3) * 4;
            if (threadIdx.x < 64)
                *(float4*)&sB[(threadIdx.x & 63) >> 2][col] =
                    *(const float4*)(xz + rb2*XZW + 512 + col);
            else
                *(float4*)&sC[(threadIdx.x & 63) >> 2][col] =
                    *(const float4*)(xz + rb2*XZW + 528 + col);
        }
        __syncthreads();
        #pragma unroll
        for (int tt = 0; tt < TT; ++tt) {
            float dtv = sdt[tt][dl];
            float xv  = sx[tt][dl];
            float u   = dtv * xv;
            float4 Bv = *(const float4*)&sB[tt][sg*4];
            float4 Cv = *(const float4*)&sC[tt][sg*4];
            float bb[4] = {Bv.x, Bv.y, Bv.z, Bv.w};
            float cc[4] = {Cv.x, Cv.y, Cv.z, Cv.w};
            float p = 0.f;
            #pragma unroll
            for (int k = 0; k < 4; ++k) {
                float dA = __expf(dtv * A[k]);
                h[k] = fmaf(dA, h[k], u * bb[k]);
                p = fmaf(h[k], cc[k], p);
            }
            p += __shfl_xor(p, 1);
            p += __shfl_xor(p, 2);
            if (sg == 0) {
                float zv = sz[tt][dl];
                float sil = zv / (1.f + __expf(-zv));
                ssm[(r0 + t0 + tt)*DM + d] = fmaf(p, sil, xv * Dv);
            }
        }
        __syncthreads();
    }
}

// ---------------- host ----------------
static inline void mgemm(hipStream_t st, const float* A, const unsigned short* W,
                         const float* bias, float* C, int M, int N, int Kp, int Kreal,
                         int lda, int ldc, int act, int accum) {
    dim3 g(M/128, (N+127)/128);
    mfma_gemm<<<g, 256, 0, st>>>(A, W, bias, C, N, Kp, Kreal, lda, ldc, act, accum);
}
static inline void gemm(hipStream_t st, const float* A, const float* W, const float* bias,
                        float* C, int M, int N, int K, int lda, int ldc, int act, int accum) {
    dim3 g(M/64, (N+63)/64);
    gemm_f32<<<g, 256, 0, st>>>(A, W, bias, C, N, K, lda, ldc, act, accum);
}

extern "C" void kernel_launch(void* const* d_in, const int* in_sizes, int n_in,
                              void* d_out, int out_size, void* d_ws, size_t ws_size,
                              hipStream_t stream) {
    (void)in_sizes; (void)n_in; (void)out_size; (void)ws_size;
    const float* obs      = (const float*)d_in[0];
    const int*   pa       = (const int*)d_in[1];
    const float* h0in[2]  = {(const float*)d_in[2], (const float*)d_in[3]};
    const float* kan_ln_g = (const float*)d_in[4];
    const float* kan_ln_b = (const float*)d_in[5];
    const float* kan_sp   = (const float*)d_in[6];
    const float* kan_sc   = (const float*)d_in[7];
    const float* kan_bias = (const float*)d_in[8];
    const float* kan_beta = (const float*)d_in[9];
    const float* fn_g     = (const float*)d_in[10];
    const float* fn_b     = (const float*)d_in[11];
    const float* gnn_W    = (const float*)d_in[12];
    const float* edge_w   = (const float*)d_in[13];
    const float* act_emb  = (const float*)d_in[14];
    const float* W_ip     = (const float*)d_in[15];
    const float* b_ip     = (const float*)d_in[16];
    const float* fl_g     = (const float*)d_in[37];
    const float* fl_b     = (const float*)d_in[38];
    const float* pW1      = (const float*)d_in[39];
    const float* pb1      = (const float*)d_in[40];
    const float* pW2      = (const float*)d_in[41];
    const float* pb2      = (const float*)d_in[42];
    const float* vW1      = (const float*)d_in[43];
    const float* vb1      = (const float*)d_in[44];
    const float* vW2      = (const float*)d_in[45];
    const float* vb2      = (const float*)d_in[46];

    // --- workspace arena (floats). Total = 26,476,544 fl == proven footprint.
    const size_t SZ_BIG = (size_t)BLR * DM;           // 4,194,304
    float* ws = (float*)d_ws;
    float* X    = ws;                                 // residual
    float* R0   = X + SZ_BIG;                         // xn / ssm; kan overlays:
    unsigned short* WIP16 = (unsigned short*)R0;                  // 256x320 bf16
    unsigned short* WF16  = WIP16 + (size_t)DM*CATP;              // 256x256 bf16 swz
    float* XZBC = R0 + SZ_BIG;                        // BLR x 800 (x|z|B|C|dt)
    unsigned short* AG16 = (unsigned short*)XZBC;     // 65536x256 bf16 swz (kan phase)
    float* R4   = XZBC + (size_t)BLR * XZW;           // cat BLRxCATD; layer overlays:
    const size_t CH = (size_t)BB * NC * DM * DS;      // 1,048,576 (NC=16)
    float* Pbuf = R4;
    float* Sbuf = R4 + CH;
    float* HIN  = R4 + 2*CH;
    unsigned short* WINX16[2];
    WINX16[0] = (unsigned short*)(R4 + 3*CH);                     // 800x256 bf16
    WINX16[1] = WINX16[0] + (size_t)XZW*DM;
    unsigned short* WOUT16[2];
    WOUT16[0] = WINX16[1] + (size_t)XZW*DM;                       // 256x256
    WOUT16[1] = WOUT16[0] + DM*DM;
    unsigned short* PW116 = WOUT16[1] + DM*DM;                    // 128x256
    unsigned short* VW116 = PW116 + 128*DM;                       // 64x256

    float* out        = (float*)d_out;
    float* out_logits = out;
    float* out_value  = out + (size_t)BLR * NACTN;
    float* out_h[2]   = {out + (size_t)BLR*NACTN + BLR,
                         out + (size_t)BLR*NACTN + BLR + (size_t)BB*DM*DS};

    // --- KAN phase (AG16 overlays XZBC; WIP/WF overlay R0) ---
    prep_wf16<<<(DM*KKANP+255)/256, 256, 0, stream>>>(kan_sp, kan_sc, WF16);
    prep_bf16<<<(DM*CATP+255)/256, 256, 0, stream>>>(W_ip, WIP16, DM, CATD, CATP);
    kan_statgen<<<BLR*NF/4, 256, 0, stream>>>(obs, kan_ln_g, kan_ln_b, kan_beta, AG16);
    kan_gemm2<<<BLR*NF/64, 256, 0, stream>>>(AG16, WF16, kan_bias, fn_g, fn_b, R4);
    graph_kernel<<<BLR, 64, 0, stream>>>(obs, gnn_W, edge_w, R4);
    gather_aemb<<<BLR*AEM/256, 256, 0, stream>>>(pa, act_emb, R4);

    // --- input projection: K=304 real, Kp=320 ---
    mgemm(stream, R4, WIP16, b_ip, X, BLR, DM, CATP, CATD, CATD, DM, 0, 0);

    // --- all weight preps (cat dead; R4 weight zone safe now) ---
    prep_bf16<<<(128*DM+255)/256, 256, 0, stream>>>(pW1, PW116, 128, DM, DM);
    prep_bf16<<<(64*DM+255)/256, 256, 0, stream>>>(vW1, VW116, 64, DM, DM);
    for (int l = 0; l < 2; ++l) {
        const float* Win  = (const float*)d_in[17 + 10*l + 2];
        const float* Wdt  = (const float*)d_in[17 + 10*l + 3];
        const float* WBp  = (const float*)d_in[17 + 10*l + 6];
        const float* WCp  = (const float*)d_in[17 + 10*l + 7];
        const float* Wout = (const float*)d_in[17 + 10*l + 9];
        prep_layerw<<<(800*256 + 256*256 + 255)/256, 256, 0, stream>>>(
            Win, WBp, WCp, Wdt, Wout, WINX16[l], WOUT16[l]);
    }

    // --- two S6 layers ---
    for (int l = 0; l < 2; ++l) {
        const float* lng  = (const float*)d_in[17 + 10*l + 0];
        const float* lnb  = (const float*)d_in[17 + 10*l + 1];
        const float* bdt  = (const float*)d_in[17 + 10*l + 4];
        const float* Alog = (const float*)d_in[17 + 10*l + 5];
        const float* Dp   = (const float*)d_in[17 + 10*l + 8];

        ln256<<<BLR/4, 256, 0, stream>>>(X, lng, lnb, R0);                       // xn
        mgemm(stream, R0, WINX16[l], bdt, XZBC, BLR, XZW, DM, DM, DM, XZW, 3, 0); // x|z|B|C|dt
        s6_chunkA<<<BB*NC*4, 256, 0, stream>>>(XZBC, Alog, Pbuf, Sbuf);
        s6_comb<<<BB*DM*DS/256, 256, 0, stream>>>(Pbuf, Sbuf, h0in[l], HIN, out_h[l]);
        s6_chunkC<<<BB*NC*4, 256, 0, stream>>>(XZBC, Alog, HIN, Dp, R0);          // ssm -> R0
        mgemm(stream, R0, WOUT16[l], nullptr, X, BLR, DM, DM, DM, DM, DM, 0, 1);  // X += ssm@Wout^T
    }

    // --- heads (scratch in dead XZBC) ---
    float* H1 = XZBC;                     // BLR x 128
    float* H2 = XZBC + (size_t)BLR*128;   // BLR x 64
    ln256<<<BLR/4, 256, 0, stream>>>(X, fl_g, fl_b, R0);
    mgemm(stream, R0, PW116, pb1, H1, BLR, 128, DM, DM, DM, 128, 1, 0);
    gemm(stream, H1, pW2, pb2, out_logits, BLR, NACTN, 128, 128, NACTN, 0, 0);
    mgemm(stream, R0, VW116, vb1, H2, BLR, 64, DM, DM, DM, 64, 1, 0);
    gemm(stream, H2, vW2, vb2, out_value, BLR, 1, 64, 64, 1, 0, 0);
}

// Round 14
// 388.968 us; speedup vs baseline: 1.6734x; 1.1968x over previous
//
#include <hip/hip_runtime.h>
#include <math.h>

// ---------------- problem constants ----------------
#define BB   16
#define LL   1024
#define BLR  (BB*LL)        // 16384 rows
#define DM   256
#define DS   16
#define FD   115
#define NF   4
#define NACTN 19
#define GH   32
#define GKN  6
#define AEM  16
#define NP   22
#define CATD 304            // cat width
#define CATP 320            // MFMA Kp for input proj
#define KKANP 256           // KAN K padded
#define KREALK 230
#define NC   16             // scan chunks
#define CL   (LL/NC)        // 64 steps per chunk
#define TT   16             // scan time-tile staged in LDS
#define LDK  40             // LDS row stride (input-proj mfma_gemm only)
#define XZW  800            // x(256) | z(256) | dt(256) | B(16) | C(16)

// r14: all K=256 GEMMs moved to bgemm<NFRAG> — fragment-swizzled bf16 operands in
// GLOBAL, zero LDS, zero barriers (r13: N=800 mfma_gemm had 1.8M LDS conflicts +
// 18% occupancy; r12's kan_gemm2 proved the swizzled pattern).
// Swizzle offset (shorts) for (row,k), K=256: (row>>4)*4096 + (k>>5)*512 +
//   ((k>>3)&3)*128 + (row&15)*8 + (k&7).
// XZBC layout: x[0:256) z[256:512) dt[512:768) B[768:784) C[784:800).
// dt/B/C are COMPOSITE-weight outputs of xn (exact: Bt = xn@(WB.Winx)^T etc).

typedef __attribute__((ext_vector_type(8))) short bf16x8;
typedef __attribute__((ext_vector_type(4))) float f32x4;

__device__ inline unsigned short f2bf(float f) {
    unsigned int u = __float_as_uint(f);
    u += 0x7fff + ((u >> 16) & 1);
    return (unsigned short)(u >> 16);
}
__device__ inline unsigned int f2bf2(float lo, float hi) {
    return (unsigned int)f2bf(lo) | ((unsigned int)f2bf(hi) << 16);
}
__device__ inline size_t swz(int row, int k) {   // K=256 fragment-order offset
    return (size_t)(row >> 4)*4096 + (k >> 5)*512 + ((k >> 3) & 3)*128
         + (row & 15)*8 + (k & 7);
}

// ============ bgemm<NFRAG>: C[M,N]=act(A16@W16^T+bias)(+C), K=256, no LDS ========
// Block: 64 rows x NFRAG*32 cols; 4 waves 2x2 (wave = 32 rows x NFRAG*16 cols).
// act: 0=none, 1=relu, 3=softplus+bdt on cols [512,768) only.
template<int NFRAG>
__global__ __launch_bounds__(256) void bgemm(
    const unsigned short* __restrict__ A, const unsigned short* __restrict__ W,
    const float* __restrict__ bias, float* __restrict__ C,
    int ldc, int act, int accum)
{
    const int tid = threadIdx.x;
    const int wid = tid >> 6, lane = tid & 63;
    const int wr = wid >> 1, wc = wid & 1;
    const int g = lane >> 4, r16 = lane & 15;
    const int bm = blockIdx.x * 64;
    const int bn = blockIdx.y * (NFRAG * 32);

    f32x4 acc[2][NFRAG] = {};
    const unsigned short* abase = A + ((size_t)(bm >> 4) + wr*2)*4096 + g*128 + r16*8;
    const unsigned short* wbase = W + ((size_t)(bn >> 4) + wc*NFRAG)*4096 + g*128 + r16*8;
    #pragma unroll
    for (int kk = 0; kk < 8; ++kk) {
        bf16x8 a0 = *(const bf16x8*)(abase + kk*512);
        bf16x8 a1 = *(const bf16x8*)(abase + 4096 + kk*512);
        bf16x8 bfr[NFRAG];
        #pragma unroll
        for (int ni = 0; ni < NFRAG; ++ni)
            bfr[ni] = *(const bf16x8*)(wbase + (size_t)ni*4096 + kk*512);
        #pragma unroll
        for (int ni = 0; ni < NFRAG; ++ni) {
            acc[0][ni] = __builtin_amdgcn_mfma_f32_16x16x32_bf16(a0, bfr[ni], acc[0][ni], 0,0,0);
            acc[1][ni] = __builtin_amdgcn_mfma_f32_16x16x32_bf16(a1, bfr[ni], acc[1][ni], 0,0,0);
        }
    }
    #pragma unroll
    for (int mi = 0; mi < 2; ++mi) {
        #pragma unroll
        for (int j = 0; j < 4; ++j) {
            int row = bm + wr*32 + mi*16 + g*4 + j;
            float* crow = C + (size_t)row * ldc;
            #pragma unroll
            for (int ni = 0; ni < NFRAG; ++ni) {
                int col = bn + wc*(NFRAG*16) + ni*16 + r16;
                float v = acc[mi][ni][j];
                if (act == 3) {
                    if (col >= 512 && col < 768) {
                        v += bias[col - 512];
                        v = fmaxf(v, 0.f) + __logf(1.f + __expf(-fabsf(v)));
                    }
                } else {
                    if (bias) v += bias[col];
                    if (act == 1) v = fmaxf(v, 0.f);
                }
                if (accum) v += crow[col];
                crow[col] = v;
            }
        }
    }
}

// ============ MFMA GEMM (input projection only: f32 A, row-major W) ============
__global__ __launch_bounds__(256) void mfma_gemm(
    const float* __restrict__ A, const unsigned short* __restrict__ W,
    const float* __restrict__ bias, float* __restrict__ C,
    int N, int Kp, int Kreal, int lda, int ldc, int act, int accum)
{
    __shared__ __align__(16) unsigned short As[128*LDK];
    __shared__ __align__(16) unsigned short Ws[128*LDK];
    const int tid = threadIdx.x;
    const int bm = blockIdx.x * 128;
    const int bn = blockIdx.y * 128;
    const int wid = tid >> 6, lane = tid & 63;
    const int wr = wid >> 1, wc = wid & 1;
    const int g = lane >> 4, r16 = lane & 15;
    const int srow = tid >> 1;
    const int shalf = (tid & 1) * 16;

    f32x4 acc[4][4] = {};
    for (int k0 = 0; k0 < Kp; k0 += 32) {
        uint4 alo = make_uint4(0u,0u,0u,0u), ahi = make_uint4(0u,0u,0u,0u);
        if (k0 + shalf < Kreal) {
            const float* ap = A + (size_t)(bm + srow) * lda + k0 + shalf;
            float4 a0 = *(const float4*)(ap);
            float4 a1 = *(const float4*)(ap + 4);
            float4 a2 = *(const float4*)(ap + 8);
            float4 a3 = *(const float4*)(ap + 12);
            alo = make_uint4(f2bf2(a0.x,a0.y), f2bf2(a0.z,a0.w),
                             f2bf2(a1.x,a1.y), f2bf2(a1.z,a1.w));
            ahi = make_uint4(f2bf2(a2.x,a2.y), f2bf2(a2.z,a2.w),
                             f2bf2(a3.x,a3.y), f2bf2(a3.z,a3.w));
        }
        unsigned short* ad = &As[srow*LDK + shalf];
        *(uint4*)(ad)     = alo;
        *(uint4*)(ad + 8) = ahi;
        int n = bn + srow;
        uint4 wv0 = make_uint4(0u,0u,0u,0u), wv1 = make_uint4(0u,0u,0u,0u);
        if (n < N) {
            const unsigned short* wp = W + (size_t)n * Kp + k0 + shalf;
            wv0 = ((const uint4*)wp)[0];
            wv1 = ((const uint4*)wp)[1];
        }
        unsigned short* wd = &Ws[srow*LDK + shalf];
        *(uint4*)(wd)     = wv0;
        *(uint4*)(wd + 8) = wv1;
        __syncthreads();

        bf16x8 af[4], bfr[4];
        #pragma unroll
        for (int mi = 0; mi < 4; ++mi)
            af[mi] = *reinterpret_cast<const bf16x8*>(&As[(wr*64 + mi*16 + r16)*LDK + g*8]);
        #pragma unroll
        for (int ni = 0; ni < 4; ++ni)
            bfr[ni] = *reinterpret_cast<const bf16x8*>(&Ws[(wc*64 + ni*16 + r16)*LDK + g*8]);
        #pragma unroll
        for (int mi = 0; mi < 4; ++mi)
            #pragma unroll
            for (int ni = 0; ni < 4; ++ni)
                acc[mi][ni] = __builtin_amdgcn_mfma_f32_16x16x32_bf16(
                    af[mi], bfr[ni], acc[mi][ni], 0, 0, 0);
        __syncthreads();
    }
    #pragma unroll
    for (int mi = 0; mi < 4; ++mi) {
        #pragma unroll
        for (int j = 0; j < 4; ++j) {
            int row = bm + wr*64 + mi*16 + g*4 + j;
            float* crow = C + (size_t)row * ldc;
            #pragma unroll
            for (int ni = 0; ni < 4; ++ni) {
                int col = bn + wc*64 + ni*16 + r16;
                if (col < N) {
                    float v = acc[mi][ni][j];
                    if (bias) v += bias[col];
                    if (act == 1) v = fmaxf(v, 0.f);
                    if (accum) v += crow[col];
                    crow[col] = v;
                }
            }
        }
    }
}

// ============ KAN stats + A-generation (fragment-swizzled bf16 out) ============
__global__ __launch_bounds__(256) void kan_statgen(
    const float* __restrict__ obs, const float* __restrict__ lng,
    const float* __restrict__ lnb, const float* __restrict__ betap,
    unsigned short* __restrict__ AG)
{
    int row = blockIdx.x * 4 + (threadIdx.x >> 6);
    int l = threadIdx.x & 63;
    const float beta = fminf(fmaxf(betap[0], 0.5f), 6.0f);
    const float* o = obs + (size_t)row * FD;
    float v0 = o[l];
    float v1 = (l + 64 < FD) ? o[l + 64] : 0.f;
    float s = v0 + v1;
    for (int off = 32; off; off >>= 1) s += __shfl_xor(s, off);
    float m = s * (1.f / FD);
    float e0 = v0 - m;
    float e1 = (l + 64 < FD) ? (v1 - m) : 0.f;
    float ss = e0*e0 + e1*e1;
    for (int off = 32; off; off >>= 1) ss += __shfl_xor(ss, off);
    float rs = rsqrtf(ss * (1.f / FD) + 1e-5f);

    float x0 = e0 * rs * lng[l] + lnb[l];
    float sb0 = 0.f;
    #pragma unroll
    for (int g5 = 0; g5 < 5; ++g5) {
        float dx = x0 - (-1.f + 0.5f * (float)g5);
        sb0 += __expf(-dx*dx*beta);
    }
    unsigned int u0 = f2bf2(x0, sb0);
    unsigned int u1 = 0u;
    if (l + 64 < FD) {
        float x1 = e1 * rs * lng[l+64] + lnb[l+64];
        float sb1 = 0.f;
        #pragma unroll
        for (int g5 = 0; g5 < 5; ++g5) {
            float dx = x1 - (-1.f + 0.5f * (float)g5);
            sb1 += __expf(-dx*dx*beta);
        }
        u1 = f2bf2(x1, sb1);
    }
    size_t base = (size_t)(row >> 4) * 4096 + (row & 15) * 8
                + ((l >> 2) & 3) * 128 + ((2*l) & 7);
    *(unsigned int*)(AG + base + ((l >> 4)    ) * 512) = u0;
    *(unsigned int*)(AG + base + ((l >> 4) + 4) * 512) = u1;
}

// ============ KAN weights -> fragment-swizzled bf16 ============
__global__ void prep_wf16(const float* __restrict__ sp, const float* __restrict__ sc,
                          unsigned short* __restrict__ Wg)
{
    int idx = blockIdx.x * 256 + threadIdx.x;
    if (idx >= DM * KKANP) return;
    int o = idx >> 8, k = idx & 255;
    float v = 0.f;
    if (k < KREALK) {
        int i = k >> 1;
        if (k & 1) {
            const float* s5 = sp + ((size_t)o*FD + i)*5;
            v = s5[0] + s5[1] + s5[2] + s5[3] + s5[4];
        } else v = sc[o*FD + i];
    }
    Wg[swz(o, k)] = f2bf(v);
}

// ============ KAN GEMM (proven no-LDS) -> cat[0:256] ============
__global__ __launch_bounds__(256) void kan_gemm2(
    const unsigned short* __restrict__ AG, const unsigned short* __restrict__ WF,
    const float* __restrict__ kbias, const float* __restrict__ fng,
    const float* __restrict__ fnb, float* __restrict__ cat)
{
    __shared__ float rsum[64][2];
    __shared__ float rsq[64][2];
    const int tid = threadIdx.x;
    const int bm = blockIdx.x * 64;
    const int wid = tid >> 6, lane = tid & 63;
    const int wr = wid >> 1, wc = wid & 1;
    const int g = lane >> 4, r16 = lane & 15;

    f32x4 acc[2][8] = {};
    const unsigned short* abase = AG + ((size_t)(bm >> 4) + wr*2)*4096 + g*128 + r16*8;
    const unsigned short* wbase = WF + (size_t)(wc*8)*4096 + g*128 + r16*8;
    #pragma unroll
    for (int kk = 0; kk < 8; ++kk) {
        bf16x8 af0 = *(const bf16x8*)(abase + kk*512);
        bf16x8 af1 = *(const bf16x8*)(abase + 4096 + kk*512);
        bf16x8 bfr[8];
        #pragma unroll
        for (int ni = 0; ni < 8; ++ni)
            bfr[ni] = *(const bf16x8*)(wbase + (size_t)ni*4096 + kk*512);
        #pragma unroll
        for (int ni = 0; ni < 8; ++ni) {
            acc[0][ni] = __builtin_amdgcn_mfma_f32_16x16x32_bf16(af0, bfr[ni], acc[0][ni], 0,0,0);
            acc[1][ni] = __builtin_amdgcn_mfma_f32_16x16x32_bf16(af1, bfr[ni], acc[1][ni], 0,0,0);
        }
    }
    float bias8[8], g8[8], b8[8];
    #pragma unroll
    for (int ni = 0; ni < 8; ++ni) {
        int col = wc*128 + ni*16 + r16;
        bias8[ni] = kbias[col]; g8[ni] = fng[col]; b8[ni] = fnb[col];
    }
    #pragma unroll
    for (int mi = 0; mi < 2; ++mi) {
        #pragma unroll
        for (int j = 0; j < 4; ++j) {
            float s = 0.f, q = 0.f;
            #pragma unroll
            for (int ni = 0; ni < 8; ++ni) {
                float v = acc[mi][ni][j] + bias8[ni];
                s += v; q += v*v;
            }
            #pragma unroll
            for (int off = 1; off < 16; off <<= 1) {
                s += __shfl_xor(s, off);
                q += __shfl_xor(q, off);
            }
            if (r16 == 0) {
                int row = wr*32 + mi*16 + g*4 + j;
                rsum[row][wc] = s; rsq[row][wc] = q;
            }
        }
    }
    __syncthreads();
    #pragma unroll
    for (int mi = 0; mi < 2; ++mi) {
        int row0 = wr*32 + mi*16 + g*4;
        float o8[8] = {0.f,0.f,0.f,0.f,0.f,0.f,0.f,0.f};
        #pragma unroll
        for (int j = 0; j < 4; ++j) {
            int row = row0 + j;
            float sm = rsum[row][0] + rsum[row][1];
            float sq = rsq[row][0] + rsq[row][1];
            float mn = sm * (1.f/256.f);
            float var = fmaxf(sq * (1.f/256.f) - mn*mn, 0.f);
            float rstd = rsqrtf(var + 1e-5f);
            #pragma unroll
            for (int ni = 0; ni < 8; ++ni) {
                float v = acc[mi][ni][j] + bias8[ni];
                v = (v - mn) * rstd * g8[ni] + b8[ni];
                o8[ni] += fmaxf(v, 0.f);
            }
        }
        int rbl = (bm + row0) >> 2;
        float* crow = cat + (size_t)rbl * CATD;
        #pragma unroll
        for (int ni = 0; ni < 8; ++ni)
            crow[wc*128 + ni*16 + r16] = o8[ni] * 0.25f;
    }
}

// ---------------- generic f32 GEMM (tiny N: heads) ----------------
__global__ __launch_bounds__(256) void gemm_f32(
    const float* __restrict__ A, const float* __restrict__ W,
    const float* __restrict__ bias, float* __restrict__ C,
    int N, int K, int lda, int ldc, int act, int accum)
{
    __shared__ float As[16][68];
    __shared__ float Ws[16][68];
    const int tid = threadIdx.x;
    const int bm = blockIdx.x * 64;
    const int bn = blockIdx.y * 64;
    const int ty = tid >> 4, tx = tid & 15;
    const int lr = tid >> 2;
    const int lk = (tid & 3) * 4;
    float acc[4][4] = {{0.f,0.f,0.f,0.f},{0.f,0.f,0.f,0.f},{0.f,0.f,0.f,0.f},{0.f,0.f,0.f,0.f}};

    for (int k0 = 0; k0 < K; k0 += 16) {
        float4 av = *reinterpret_cast<const float4*>(A + (size_t)(bm + lr) * lda + k0 + lk);
        As[lk+0][lr] = av.x; As[lk+1][lr] = av.y; As[lk+2][lr] = av.z; As[lk+3][lr] = av.w;
        float4 wv = make_float4(0.f, 0.f, 0.f, 0.f);
        if (bn + lr < N)
            wv = *reinterpret_cast<const float4*>(W + (size_t)(bn + lr) * K + k0 + lk);
        Ws[lk+0][lr] = wv.x; Ws[lk+1][lr] = wv.y; Ws[lk+2][lr] = wv.z; Ws[lk+3][lr] = wv.w;
        __syncthreads();
        #pragma unroll
        for (int kk = 0; kk < 16; ++kk) {
            float4 a4 = *reinterpret_cast<const float4*>(&As[kk][ty*4]);
            float4 b4 = *reinterpret_cast<const float4*>(&Ws[kk][tx*4]);
            float aa[4] = {a4.x, a4.y, a4.z, a4.w};
            float bb[4] = {b4.x, b4.y, b4.z, b4.w};
            #pragma unroll
            for (int i = 0; i < 4; ++i)
                #pragma unroll
                for (int j = 0; j < 4; ++j)
                    acc[i][j] = fmaf(aa[i], bb[j], acc[i][j]);
        }
        __syncthreads();
    }
    #pragma unroll
    for (int i = 0; i < 4; ++i) {
        int row = bm + ty*4 + i;
        #pragma unroll
        for (int j = 0; j < 4; ++j) {
            int col = bn + tx*4 + j;
            if (col < N) {
                float v = acc[i][j];
                if (bias) v += bias[col];
                if (act == 1) v = fmaxf(v, 0.f);
                size_t o = (size_t)row * ldc + col;
                if (accum) v += C[o];
                C[o] = v;
            }
        }
    }
}

// ---------------- prep kernels ----------------
__global__ void prep_bf16(const float* __restrict__ src, unsigned short* __restrict__ dst,
                          int N, int K, int Kp)   // row-major (input proj)
{
    int idx = blockIdx.x * 256 + threadIdx.x;
    if (idx >= N * Kp) return;
    int n = idx / Kp, k = idx - n * Kp;
    dst[idx] = (k < K) ? f2bf(src[(size_t)n * K + k]) : (unsigned short)0;
}

__global__ void prep_bf16_swz(const float* __restrict__ src,
                              unsigned short* __restrict__ dst, int N)  // K=256
{
    int idx = blockIdx.x * 256 + threadIdx.x;
    if (idx >= N * DM) return;
    int n = idx >> 8, k = idx & 255;
    dst[swz(n, k)] = f2bf(src[idx]);
}

// Per-layer: WINX16 swizzled rows 0..799 = [Win(512) | Wdt.Winx(256) | WB.Winx(16)
// | WC.Winx(16)] mapped to cols x|z|dt|B|C; WOUT16 swizzled.
__global__ void prep_layerw(
    const float* __restrict__ Win, const float* __restrict__ WB,
    const float* __restrict__ WC, const float* __restrict__ Wdt,
    const float* __restrict__ Wout,
    unsigned short* __restrict__ WINX16, unsigned short* __restrict__ WOUT16)
{
    int idx = blockIdx.x * 256 + threadIdx.x;
    if (idx < 512*256) {                        // Win rows 0..511
        int n = idx >> 8, k = idx & 255;
        WINX16[swz(n, k)] = f2bf(Win[idx]);
    } else if (idx < 768*256) {                 // dt composite rows 512..767
        int j2 = idx - 512*256;
        int n = j2 >> 8, k = j2 & 255;
        const float* src = Wdt + (size_t)n*DM;
        float acc = 0.f;
        for (int j = 0; j < DM; ++j)
            acc = fmaf(src[j], Win[(size_t)j*DM + k], acc);
        WINX16[swz(512 + n, k)] = f2bf(acc);
    } else if (idx < 800*256) {                 // B|C composite rows 768..799
        int j2 = idx - 768*256;
        int n = j2 >> 8, k = j2 & 255;
        const float* src = (n < 16) ? (WB + n*DM) : (WC + (n-16)*DM);
        float acc = 0.f;
        for (int j = 0; j < DM; ++j)
            acc = fmaf(src[j], Win[(size_t)j*DM + k], acc);
        WINX16[swz(768 + n, k)] = f2bf(acc);
    } else if (idx < 800*256 + 256*256) {       // Wout swizzled
        int j2 = idx - 800*256;
        int n = j2 >> 8, k = j2 & 255;
        WOUT16[swz(n, k)] = f2bf(Wout[j2]);
    }
}

// ---------------- graph feature -> cat[256:288] ----------------
__global__ __launch_bounds__(64) void graph_kernel(const float* __restrict__ obs,
    const float* __restrict__ gW, const float* __restrict__ ewp,
    float* __restrict__ out)
{
    __shared__ float px[NP], py[NP];
    __shared__ float nodes[NP][8];
    __shared__ float gxs[NP][GH];
    __shared__ unsigned int msk[NP];
    __shared__ float rden[NP];
    __shared__ float wgt[NP];
    const int row = blockIdx.x;
    const int lane = threadIdx.x;
    const float* fc = obs + ((size_t)row * NF + 3) * FD;
    const float* fp = obs + ((size_t)row * NF + 2) * FD;
    const float ew = ewp[0];

    if (lane < NP) {
        int i = lane;
        float p0, p1, q0, q1;
        if (i < 11) { p0 = fc[3+2*i];  p1 = fc[4+2*i];  q0 = fp[3+2*i];  q1 = fp[4+2*i]; }
        else { int ii = i-11; p0 = fc[25+2*ii]; p1 = fc[26+2*ii]; q0 = fp[25+2*ii]; q1 = fp[26+2*ii]; }
        px[i] = p0; py[i] = p1;
        float bx = fc[0], by = fc[1];
        float bd = sqrtf((p0-bx)*(p0-bx) + (p1-by)*(p1-by));
        nodes[i][0] = p0; nodes[i][1] = p1;
        nodes[i][2] = p0 - q0; nodes[i][3] = p1 - q1;
        nodes[i][4] = (i < 11) ? 0.f : 1.f;
        nodes[i][5] = __expf(-2.f * bd);
    }
    __syncthreads();
    if (lane < NP) {
        int base = (lane < 11) ? 0 : 11;
        float cx = 0.f, cy = 0.f;
        for (int j = 0; j < 11; ++j) { cx += px[base+j]; cy += py[base+j]; }
        cx *= (1.f/11.f); cy *= (1.f/11.f);
        nodes[lane][6] = px[lane] - cx;
        nodes[lane][7] = py[lane] - cy;
        unsigned sel = 0;
        for (int k = 0; k < GKN; ++k) {
            float best = 1e30f; int bj = 0;
            for (int j = 0; j < NP; ++j) {
                if (j == lane || ((sel >> j) & 1u)) continue;
                float dx = px[lane]-px[j], dy = py[lane]-py[j];
                float dd = sqrtf(dx*dx + dy*dy);
                if (dd < best) { best = dd; bj = j; }
            }
            sel |= (1u << bj);
        }
        unsigned full = sel | (1u << lane);
        msk[lane] = full;
        rden[lane] = 1.f / fmaxf((float)__popc(full), 1.f);
    }
    __syncthreads();
    for (int idx = lane; idx < NP*GH; idx += 64) {
        int i = idx >> 5, h = idx & 31;
        float s = 0.f;
        #pragma unroll
        for (int f = 0; f < 8; ++f) s += nodes[i][f] * gW[h*8 + f];
        gxs[i][h] = s;
    }
    __syncthreads();
    if (lane < NP) {
        float s = 0.f;
        for (int i = 0; i < NP; ++i) if ((msk[i] >> lane) & 1u) s += rden[i];
        wgt[lane] = (1.f - ew) + ew * s;
    }
    __syncthreads();
    if (lane < GH) {
        float s = 0.f;
        for (int j = 0; j < NP; ++j) s += wgt[j] * gxs[j][lane];
        out[(size_t)row * CATD + DM + lane] = s * (1.f/22.f);
    }
}

// ---------------- action embedding gather -> cat[288:304] ----------------
__global__ void gather_aemb(const int* __restrict__ pa, const float* __restrict__ emb,
                            float* __restrict__ out)
{
    int idx = blockIdx.x * 256 + threadIdx.x;
    int row = idx >> 4, e = idx & 15;
    out[(size_t)row * CATD + DM + GH + e] = emb[pa[row]*AEM + e];
}

// ---------------- LN over 256 cols -> fragment-swizzled bf16 ----------------
__global__ __launch_bounds__(256) void ln256_swz(const float* __restrict__ X,
    const float* __restrict__ g, const float* __restrict__ b,
    unsigned short* __restrict__ Y16)
{
    int row = blockIdx.x * 4 + (threadIdx.x >> 6);
    int lane = threadIdx.x & 63;
    const float* x = X + (size_t)row * DM;
    float4 v = reinterpret_cast<const float4*>(x)[lane];
    float s = v.x + v.y + v.z + v.w;
    for (int off = 32; off; off >>= 1) s += __shfl_xor(s, off);
    float m = s * (1.f / DM);
    float d0 = v.x-m, d1 = v.y-m, d2 = v.z-m, d3 = v.w-m;
    float ss = d0*d0 + d1*d1 + d2*d2 + d3*d3;
    for (int off = 32; off; off >>= 1) ss += __shfl_xor(ss, off);
    float rstd = rsqrtf(ss * (1.f / DM) + 1e-5f);
    int c = lane * 4;
    float o0 = d0*rstd*g[c+0] + b[c+0];
    float o1 = d1*rstd*g[c+1] + b[c+1];
    float o2 = d2*rstd*g[c+2] + b[c+2];
    float o3 = d3*rstd*g[c+3] + b[c+3];
    size_t base = swz(row, c);          // c%4==0; (c&7) in {0,4}: 8B-aligned pair
    *(uint2*)(Y16 + base) = make_uint2(f2bf2(o0, o1), f2bf2(o2, o3));
}

// ======== S6 chunked parallel scan: 4 s-states/thread, 64 d/block ========
// XZBC: x[0:256) z[256:512) dt[512:768) B[768:784) C[784:800).
__global__ __launch_bounds__(256) void s6_chunkA(
    const float* __restrict__ xz, const float* __restrict__ Alog,
    float* __restrict__ P, float* __restrict__ S)
{
    __shared__ float sdt[TT][64], sx[TT][64];
    __shared__ __align__(16) float sB[TT][16];
    const int blk = blockIdx.x;
    const int dblk = blk & 3, c = (blk >> 2) & 15, b = blk >> 6;
    const int sg = threadIdx.x & 3, dl = threadIdx.x >> 2;
    const int d0 = dblk*64, d = d0 + dl;
    float A[4];
    #pragma unroll
    for (int k = 0; k < 4; ++k) A[k] = -__expf(Alog[d*DS + sg*4 + k]);
    const size_t r0 = (size_t)b*LL + c*CL;
    const int lt = threadIdx.x >> 4, lc = (threadIdx.x & 15) * 4;
    float Pv[4] = {1.f,1.f,1.f,1.f}, Sv[4] = {0.f,0.f,0.f,0.f};
    for (int t0 = 0; t0 < CL; t0 += TT) {
        size_t rb = r0 + t0 + lt;
        *(float4*)&sdt[lt][lc] = *(const float4*)(xz + rb*XZW + 512 + d0 + lc);
        *(float4*)&sx[lt][lc]  = *(const float4*)(xz + rb*XZW + d0 + lc);
        if (threadIdx.x < 64) {
            size_t rb2 = r0 + t0 + (threadIdx.x >> 2);
            *(float4*)&sB[threadIdx.x >> 2][(threadIdx.x & 3)*4] =
                *(const float4*)(xz + rb2*XZW + 768 + (threadIdx.x & 3)*4);
        }
        __syncthreads();
        #pragma unroll
        for (int tt = 0; tt < TT; ++tt) {
            float dtv = sdt[tt][dl];
            float u   = dtv * sx[tt][dl];
            float4 Bv = *(const float4*)&sB[tt][sg*4];
            float bb[4] = {Bv.x, Bv.y, Bv.z, Bv.w};
            #pragma unroll
            for (int k = 0; k < 4; ++k) {
                float dA = __expf(dtv * A[k]);
                Pv[k] *= dA;
                Sv[k] = fmaf(dA, Sv[k], u * bb[k]);
            }
        }
        __syncthreads();
    }
    size_t o = (((size_t)b*NC + c)*DM + d)*DS + sg*4;
    *(float4*)(P + o) = make_float4(Pv[0], Pv[1], Pv[2], Pv[3]);
    *(float4*)(S + o) = make_float4(Sv[0], Sv[1], Sv[2], Sv[3]);
}

__global__ __launch_bounds__(256) void s6_comb(
    const float* __restrict__ P, const float* __restrict__ S,
    const float* __restrict__ h0, float* __restrict__ hin, float* __restrict__ hout)
{
    int idx = blockIdx.x * 256 + threadIdx.x;
    int b = idx >> 12, ds = idx & 4095;
    float h = h0[idx];
    #pragma unroll
    for (int c = 0; c < NC; ++c) {
        size_t o = (((size_t)b*NC + c) << 12) + ds;
        hin[o] = h;
        h = fmaf(P[o], h, S[o]);
    }
    hout[idx] = h;
}

// ssm output: fragment-swizzled bf16 (feeds wout bgemm directly).
__global__ __launch_bounds__(256) void s6_chunkC(
    const float* __restrict__ xz, const float* __restrict__ Alog,
    const float* __restrict__ hin, const float* __restrict__ Dp,
    unsigned short* __restrict__ ssm16)
{
    __shared__ float sdt[TT][64], sx[TT][64], sz[TT][64];
    __shared__ __align__(16) float sB[TT][16], sC[TT][16];
    const int blk = blockIdx.x;
    const int dblk = blk & 3, c = (blk >> 2) & 15, b = blk >> 6;
    const int sg = threadIdx.x & 3, dl = threadIdx.x >> 2;
    const int d0 = dblk*64, d = d0 + dl;
    float A[4];
    #pragma unroll
    for (int k = 0; k < 4; ++k) A[k] = -__expf(Alog[d*DS + sg*4 + k]);
    const float Dv = Dp[d];
    const size_t r0 = (size_t)b*LL + c*CL;
    const int lt = threadIdx.x >> 4, lc = (threadIdx.x & 15) * 4;
    float4 h4 = *(const float4*)(hin + (((size_t)b*NC + c)*DM + d)*DS + sg*4);
    float h[4] = {h4.x, h4.y, h4.z, h4.w};
    for (int t0 = 0; t0 < CL; t0 += TT) {
        size_t rb = r0 + t0 + lt;
        *(float4*)&sdt[lt][lc] = *(const float4*)(xz + rb*XZW + 512 + d0 + lc);
        *(float4*)&sx[lt][lc]  = *(const float4*)(xz + rb*XZW + d0 + lc);
        *(float4*)&sz[lt][lc]  = *(const float4*)(xz + rb*XZW + 256 + d0 + lc);
        if (threadIdx.x < 128) {
            size_t rb2 = r0 + t0 + ((threadIdx.x & 63) >> 2);
            int col = (threadIdx.x & 3) * 4;
            if (threadIdx.x < 64)
                *(float4*)&sB[(threadIdx.x & 63) >> 2][col] =
                    *(const float4*)(xz + rb2*XZW + 768 + col);
            else
                *(float4*)&sC[(threadIdx.x & 63) >> 2][col] =
                    *(const float4*)(xz + rb2*XZW + 784 + col);
        }
        __syncthreads();
        #pragma unroll
        for (int tt = 0; tt < TT; ++tt) {
            float dtv = sdt[tt][dl];
            float xv  = sx[tt][dl];
            float u   = dtv * xv;
            float4 Bv = *(const float4*)&sB[tt][sg*4];
            float4 Cv = *(const float4*)&sC[tt][sg*4];
            float bb[4] = {Bv.x, Bv.y, Bv.z, Bv.w};
            float cc[4] = {Cv.x, Cv.y, Cv.z, Cv.w};
            float p = 0.f;
            #pragma unroll
            for (int k = 0; k < 4; ++k) {
                float dA = __expf(dtv * A[k]);
                h[k] = fmaf(dA, h[k], u * bb[k]);
                p = fmaf(h[k], cc[k], p);
            }
            p += __shfl_xor(p, 1);
            p += __shfl_xor(p, 2);
            if (sg == 0) {
                float zv = sz[tt][dl];
                float sil = zv / (1.f + __expf(-zv));
                int row = (int)(r0 + t0 + tt);
                ssm16[swz(row, d)] = f2bf(fmaf(p, sil, xv * Dv));
            }
        }
        __syncthreads();
    }
}

// ---------------- host ----------------
static inline void mgemm(hipStream_t st, const float* A, const unsigned short* W,
                         const float* bias, float* C, int M, int N, int Kp, int Kreal,
                         int lda, int ldc, int act, int accum) {
    dim3 g(M/128, (N+127)/128);
    mfma_gemm<<<g, 256, 0, st>>>(A, W, bias, C, N, Kp, Kreal, lda, ldc, act, accum);
}
static inline void gemm(hipStream_t st, const float* A, const float* W, const float* bias,
                        float* C, int M, int N, int K, int lda, int ldc, int act, int accum) {
    dim3 g(M/64, (N+63)/64);
    gemm_f32<<<g, 256, 0, st>>>(A, W, bias, C, N, K, lda, ldc, act, accum);
}

extern "C" void kernel_launch(void* const* d_in, const int* in_sizes, int n_in,
                              void* d_out, int out_size, void* d_ws, size_t ws_size,
                              hipStream_t stream) {
    (void)in_sizes; (void)n_in; (void)out_size; (void)ws_size;
    const float* obs      = (const float*)d_in[0];
    const int*   pa       = (const int*)d_in[1];
    const float* h0in[2]  = {(const float*)d_in[2], (const float*)d_in[3]};
    const float* kan_ln_g = (const float*)d_in[4];
    const float* kan_ln_b = (const float*)d_in[5];
    const float* kan_sp   = (const float*)d_in[6];
    const float* kan_sc   = (const float*)d_in[7];
    const float* kan_bias = (const float*)d_in[8];
    const float* kan_beta = (const float*)d_in[9];
    const float* fn_g     = (const float*)d_in[10];
    const float* fn_b     = (const float*)d_in[11];
    const float* gnn_W    = (const float*)d_in[12];
    const float* edge_w   = (const float*)d_in[13];
    const float* act_emb  = (const float*)d_in[14];
    const float* W_ip     = (const float*)d_in[15];
    const float* b_ip     = (const float*)d_in[16];
    const float* fl_g     = (const float*)d_in[37];
    const float* fl_b     = (const float*)d_in[38];
    const float* pW1      = (const float*)d_in[39];
    const float* pb1      = (const float*)d_in[40];
    const float* pW2      = (const float*)d_in[41];
    const float* pb2      = (const float*)d_in[42];
    const float* vW1      = (const float*)d_in[43];
    const float* vb1      = (const float*)d_in[44];
    const float* vW2      = (const float*)d_in[45];
    const float* vb2      = (const float*)d_in[46];

    // --- workspace arena (floats). Total = 26,476,544 fl == proven footprint.
    const size_t SZ_BIG = (size_t)BLR * DM;           // 4,194,304
    float* ws = (float*)d_ws;
    float* X    = ws;                                 // residual (f32)
    float* R0   = X + SZ_BIG;                         // split: XN16 | SSM16 (bf16)
    unsigned short* XN16  = (unsigned short*)R0;                  // BLRx256 bf16 swz
    unsigned short* SSM16 = XN16 + (size_t)BLR*DM;                // BLRx256 bf16 swz
    // kan-phase overlays of R0:
    unsigned short* WIP16 = (unsigned short*)R0;                  // 256x320 row-major
    unsigned short* WF16  = WIP16 + (size_t)DM*CATP;              // 256x256 swz
    float* XZBC = R0 + SZ_BIG;                        // BLR x 800
    unsigned short* AG16 = (unsigned short*)XZBC;     // 65536x256 bf16 swz (kan phase)
    float* R4   = XZBC + (size_t)BLR * XZW;           // cat BLRxCATD; layer overlays:
    const size_t CH = (size_t)BB * NC * DM * DS;      // 1,048,576 (NC=16)
    float* Pbuf = R4;
    float* Sbuf = R4 + CH;
    float* HIN  = R4 + 2*CH;
    unsigned short* WINX16[2];
    WINX16[0] = (unsigned short*)(R4 + 3*CH);                     // 800x256 swz
    WINX16[1] = WINX16[0] + (size_t)XZW*DM;
    unsigned short* WOUT16[2];
    WOUT16[0] = WINX16[1] + (size_t)XZW*DM;                       // 256x256 swz
    WOUT16[1] = WOUT16[0] + DM*DM;
    unsigned short* PW116 = WOUT16[1] + DM*DM;                    // 128x256 swz
    unsigned short* VW116 = PW116 + 128*DM;                       // 64x256 swz

    float* out        = (float*)d_out;
    float* out_logits = out;
    float* out_value  = out + (size_t)BLR * NACTN;
    float* out_h[2]   = {out + (size_t)BLR*NACTN + BLR,
                         out + (size_t)BLR*NACTN + BLR + (size_t)BB*DM*DS};

    // --- KAN phase (AG16 overlays XZBC; WIP/WF overlay R0) ---
    prep_wf16<<<(DM*KKANP+255)/256, 256, 0, stream>>>(kan_sp, kan_sc, WF16);
    prep_bf16<<<(DM*CATP+255)/256, 256, 0, stream>>>(W_ip, WIP16, DM, CATD, CATP);
    kan_statgen<<<BLR*NF/4, 256, 0, stream>>>(obs, kan_ln_g, kan_ln_b, kan_beta, AG16);
    kan_gemm2<<<BLR*NF/64, 256, 0, stream>>>(AG16, WF16, kan_bias, fn_g, fn_b, R4);
    graph_kernel<<<BLR, 64, 0, stream>>>(obs, gnn_W, edge_w, R4);
    gather_aemb<<<BLR*AEM/256, 256, 0, stream>>>(pa, act_emb, R4);

    // --- input projection: cat f32 (K=304 real, Kp=320) -> X ---
    mgemm(stream, R4, WIP16, b_ip, X, BLR, DM, CATP, CATD, CATD, DM, 0, 0);

    // --- all weight preps (cat dead; R4 weight zone safe; R0 overlays dead) ---
    prep_bf16_swz<<<(128*DM+255)/256, 256, 0, stream>>>(pW1, PW116, 128);
    prep_bf16_swz<<<(64*DM+255)/256, 256, 0, stream>>>(vW1, VW116, 64);
    for (int l = 0; l < 2; ++l) {
        const float* Win  = (const float*)d_in[17 + 10*l + 2];
        const float* Wdt  = (const float*)d_in[17 + 10*l + 3];
        const float* WBp  = (const float*)d_in[17 + 10*l + 6];
        const float* WCp  = (const float*)d_in[17 + 10*l + 7];
        const float* Wout = (const float*)d_in[17 + 10*l + 9];
        prep_layerw<<<(800*256 + 256*256 + 255)/256, 256, 0, stream>>>(
            Win, WBp, WCp, Wdt, Wout, WINX16[l], WOUT16[l]);
    }

    // --- two S6 layers ---
    for (int l = 0; l < 2; ++l) {
        const float* lng  = (const float*)d_in[17 + 10*l + 0];
        const float* lnb  = (const float*)d_in[17 + 10*l + 1];
        const float* bdt  = (const float*)d_in[17 + 10*l + 4];
        const float* Alog = (const float*)d_in[17 + 10*l + 5];
        const float* Dp   = (const float*)d_in[17 + 10*l + 8];

        ln256_swz<<<BLR/4, 256, 0, stream>>>(X, lng, lnb, XN16);                  // xn (swz bf16)
        bgemm<5><<<dim3(BLR/64, 5), 256, 0, stream>>>(
            XN16, WINX16[l], bdt, XZBC, XZW, 3, 0);                               // x|z|dt|B|C
        s6_chunkA<<<BB*NC*4, 256, 0, stream>>>(XZBC, Alog, Pbuf, Sbuf);
        s6_comb<<<BB*DM*DS/256, 256, 0, stream>>>(Pbuf, Sbuf, h0in[l], HIN, out_h[l]);
        s6_chunkC<<<BB*NC*4, 256, 0, stream>>>(XZBC, Alog, HIN, Dp, SSM16);       // ssm (swz bf16)
        bgemm<4><<<dim3(BLR/64, 2), 256, 0, stream>>>(
            SSM16, WOUT16[l], nullptr, X, DM, 0, 1);                              // X += ssm@Wout^T
    }

    // --- heads (scratch in dead XZBC) ---
    float* H1 = XZBC;                     // BLR x 128
    float* H2 = XZBC + (size_t)BLR*128;   // BLR x 64
    ln256_swz<<<BLR/4, 256, 0, stream>>>(X, fl_g, fl_b, XN16);
    bgemm<4><<<dim3(BLR/64, 1), 256, 0, stream>>>(XN16, PW116, pb1, H1, 128, 1, 0);
    gemm(stream, H1, pW2, pb2, out_logits, BLR, NACTN, 128, 128, NACTN, 0, 0);
    bgemm<2><<<dim3(BLR/64, 1), 256, 0, stream>>>(XN16, VW116, vb1, H2, 64, 1, 0);
    gemm(stream, H2, vW2, vb2, out_value, BLR, 1, 64, 64, 1, 0, 0);
}